// Round 10
// baseline (751.259 us; speedup 1.0000x reference)
//
#include <hip/hip_runtime.h>
#include <hip/hip_bf16.h>

typedef __hip_bfloat16 bf16;

#define NC_ 100000
#define EC_ 1600000
#define NS_ 50000
#define ES_ 800000
#define G_  1024
#define EPS_ 1e-5f

#define NB_C 782          // ceil(100000/128)
#define NB_S 391          // ceil(50000/128)
#define NBMAX 782
#define KSL 16            // LDS slots per bucket in k_bin

#define WS_REQUIRED 39748624ull

__device__ __forceinline__ float b2f(bf16 v) { return __bfloat162float(v); }

__device__ __forceinline__ void acc8(float* a, uint4 r) {
    a[0] += __uint_as_float(r.x << 16); a[1] += __uint_as_float(r.x & 0xffff0000u);
    a[2] += __uint_as_float(r.y << 16); a[3] += __uint_as_float(r.y & 0xffff0000u);
    a[4] += __uint_as_float(r.z << 16); a[5] += __uint_as_float(r.z & 0xffff0000u);
    a[6] += __uint_as_float(r.w << 16); a[7] += __uint_as_float(r.w & 0xffff0000u);
}

__global__ void DualGNN_31327491457689_kernel() {}

__global__ __launch_bounds__(256) void k_fillout(float* out, float val, int n) {
    int i = blockIdx.x * 256 + threadIdx.x;
    if (i < n) out[i] = val;
}

__global__ __launch_bounds__(256) void k_zero(int* p, int n) {
    int i = blockIdx.x * 256 + threadIdx.x;
    int stride = gridDim.x * 256;
    while (i < n) { p[i] = 0; i += stride; }
}

// ---- Phase A: bucket histogram (LDS-staged) ----------------------------
__global__ __launch_bounds__(256) void k_bhist(const int* dst, int* bcnt, int E, int NB) {
    __shared__ int h[NBMAX];
    int t = threadIdx.x;
    for (int i = t; i < NB; i += 256) h[i] = 0;
    __syncthreads();
    for (int e = blockIdx.x * 256 + t; e < E; e += gridDim.x * 256)
        atomicAdd(&h[dst[e] >> 7], 1);
    __syncthreads();
    for (int i = t; i < NB; i += 256) {
        int v = h[i];
        if (v) atomicAdd(&bcnt[i], v);
    }
}

// ---- Phase B: scan bucket counts (both branches, one block) ------------
__device__ void scan_one(const int* cnt, int* base, int* cur, int NB, int (*sc)[1024]) {
    int t = threadIdx.x;
    for (int i = t; i < 1024; i += 256) sc[0][i] = (i < NB) ? cnt[i] : 0;
    __syncthreads();
    int pin = 0;
    for (int off = 1; off < 1024; off <<= 1) {
        for (int i = t; i < 1024; i += 256) {
            int v = sc[pin][i];
            if (i >= off) v += sc[pin][i - off];
            sc[1 - pin][i] = v;
        }
        __syncthreads();
        pin ^= 1;
    }
    for (int i = t; i <= NB; i += 256) {
        int e = (i == 0) ? 0 : sc[pin][i - 1];
        base[i] = e;
        if (i < NB) cur[i] = e;
    }
    __syncthreads();
}

__global__ __launch_bounds__(256) void k_bscan(const int* cnt_c, int* base_c, int* cur_c, int NBc,
                                               const int* cnt_s, int* base_s, int* cur_s, int NBs) {
    __shared__ int sc[2][1024];
    scan_one(cnt_c, base_c, cur_c, NBc, sc);
    scan_one(cnt_s, base_s, cur_s, NBs, sc);
}

// ---- Phase C: bin packed edges into bucket-partitioned streams ---------
// packed edge: (dst & 127) << 24 | src   (src < 2^24)
__global__ __launch_bounds__(256) void k_bin(const int* src, const int* dst, int* bcur,
                                             int* ebuf, int E, int NB, int CHUNK) {
    __shared__ int cnt[NBMAX];
    __shared__ int slot[NBMAX * KSL];    // 782*16*4 = 50 KB
    int t = threadIdx.x;
    for (long long base = (long long)blockIdx.x * CHUNK; base < E;
         base += (long long)gridDim.x * CHUNK) {
        for (int i = t; i < NB; i += 256) cnt[i] = 0;
        __syncthreads();
        int e1 = (int)base + CHUNK;
        if (e1 > E) e1 = E;
        for (int e = (int)base + t; e < e1; e += 256) {
            int d = dst[e];
            int p = ((d & 127) << 24) | src[e];
            int b = d >> 7;
            int sl = atomicAdd(&cnt[b], 1);
            if (sl < KSL) slot[b * KSL + sl] = p;
            else { int gp = atomicAdd(&bcur[b], 1); ebuf[gp] = p; }  // rare overflow
        }
        __syncthreads();
        for (int b = t; b < NB; b += 256) {
            int c = cnt[b];
            if (c > KSL) c = KSL;
            if (c > 0) {
                int gp = atomicAdd(&bcur[b], c);
                for (int k = 0; k < c; k++) ebuf[gp + k] = slot[b * KSL + k];
            }
        }
        __syncthreads();
    }
}

// ---- Phase D: per-bucket deg/start/csr build + fused layer-0 prep ------
// also writes u[i][0..7] = dinv_i * x[i][k] (bf16x8, 16 B/row)
__global__ __launch_bounds__(256) void k_build(const int* bbase, const int* ebuf,
                                               const float* x, bf16* u,
                                               int* deg, int* start, int* csr, int N) {
    __shared__ int lcnt[128], lofs[128], lcur[128];
    int b = blockIdx.x, t = threadIdx.x;
    int e0 = bbase[b], e1 = bbase[b + 1];
    int n0 = b << 7;
    if (t < 128) lcnt[t] = 0;
    __syncthreads();
    for (int e = e0 + t; e < e1; e += 256)
        atomicAdd(&lcnt[((unsigned)ebuf[e]) >> 24], 1);
    __syncthreads();
    if (t < 64) {   // exclusive scan of 128 values, 2 per lane
        int v0 = lcnt[2 * t], v1 = lcnt[2 * t + 1];
        int s = v0 + v1, incl = s;
        for (int off = 1; off < 64; off <<= 1) {
            int uu = __shfl_up(incl, off);
            if (t >= off) incl += uu;
        }
        int excl = incl - s;
        lofs[2 * t] = excl;
        lofs[2 * t + 1] = excl + v0;
    }
    __syncthreads();
    if (t < 128) {
        int node = n0 + t;
        if (node < N) {
            deg[node] = lcnt[t];
            start[node] = e0 + lofs[t];
            float d = rsqrtf((float)(lcnt[t] + 1));
            union __align__(16) Pack { bf16 hh[8]; uint4 v; } p;
            for (int k = 0; k < 7; k++) p.hh[k] = __float2bfloat16(x[node * 7 + k] * d);
            p.hh[7] = __float2bfloat16(0.f);
            ((uint4*)u)[node] = p.v;
        }
        lcur[t] = lofs[t];
    }
    __syncthreads();
    for (int e = e0 + t; e < e1; e += 256) {
        unsigned p = (unsigned)ebuf[e];
        int dl = p >> 24;
        int pos = atomicAdd(&lcur[dl], 1);
        csr[e0 + pos] = (int)(p & 0xFFFFFF);   // writes stay in this bucket's window
    }
}

// ---- Layer 0 gather in rank-7 space + fused 7x64 GEMM + bias + stats ---
// h[i][c] = dinv_i * ((u_i + sum_j u_j) . W0)[c] + b[c]
__global__ __launch_bounds__(256) void k_gather7(const bf16* u, const int* csr,
                                                 const int* start, const int* deg,
                                                 const float* W, const float* bias,
                                                 bf16* h, float* stat, int N) {
    __shared__ float Wsm[7 * 64];
    __shared__ float agg[256][9];        // pad to 9: conflict-free phase-A writes
    __shared__ float sm[2][4][64];
    int t = threadIdx.x, lane = t & 63, ty = t >> 6;
    for (int i = t; i < 448; i += 256) Wsm[i] = W[i];
    float b = bias[lane];
    float sum = 0.f, sq = 0.f;
    const uint4* up = (const uint4*)u;
    for (int base = blockIdx.x * 256; base < N; base += gridDim.x * 256) {
        __syncthreads();                 // agg reuse guard (also covers Wsm init)
        int i = base + t;
        float a[8] = {0.f, 0.f, 0.f, 0.f, 0.f, 0.f, 0.f, 0.f};
        if (i < N) {
            int dg = deg[i], s0 = start[i];
            acc8(a, up[i]);              // self-loop term
            int j = 0;
            for (; j + 4 <= dg; j += 4) {
                int i0 = csr[s0 + j], i1 = csr[s0 + j + 1];
                int i2 = csr[s0 + j + 2], i3 = csr[s0 + j + 3];
                uint4 r0 = up[i0], r1 = up[i1], r2 = up[i2], r3 = up[i3];
                acc8(a, r0); acc8(a, r1); acc8(a, r2); acc8(a, r3);
            }
            for (; j < dg; j++) acc8(a, up[csr[s0 + j]]);
            float di = rsqrtf((float)(dg + 1));
            for (int k = 0; k < 7; k++) a[k] *= di;
        }
        #pragma unroll
        for (int k = 0; k < 7; k++) agg[t][k] = a[k];
        __syncthreads();
        int mbase = base + ty * 64;
        for (int mm = 0; mm < 64; mm++) {
            int node = mbase + mm;
            if (node >= N) break;
            const float* ag = agg[ty * 64 + mm];
            float s = b;
            #pragma unroll
            for (int k = 0; k < 7; k++) s += ag[k] * Wsm[k * 64 + lane];
            h[(size_t)node * 64 + lane] = __float2bfloat16(s);
            sum += s; sq += s * s;
        }
    }
    sm[0][ty][lane] = sum;
    sm[1][ty][lane] = sq;
    __syncthreads();
    if (ty == 0) {
        atomicAdd(&stat[lane],      sm[0][0][lane] + sm[0][1][lane] + sm[0][2][lane] + sm[0][3][lane]);
        atomicAdd(&stat[64 + lane], sm[1][0][lane] + sm[1][1][lane] + sm[1][2][lane] + sm[1][3][lane]);
    }
}

// ---- Layer 1 GEMM, fused BN0(affine)+ReLU; writes y CHUNK-MAJOR --------
// y[(chunk*N + i)*16 + cl], chunk = c>>4, cl = c&15
__global__ __launch_bounds__(256) void k_gemm1(const bf16* h, const float* W,
                                               const float* stat, const float* gam,
                                               const float* bet, const int* deg,
                                               bf16* y, float invN, int N) {
    __shared__ float Wsm[64 * 64];
    __shared__ float AB[128];
    int t = threadIdx.x;
    int lane = t & 63;
    int ty = t >> 6;
    for (int i = t; i < 4096; i += 256) Wsm[i] = W[i];
    if (t < 64) {
        float mean = stat[t] * invN;
        float var = stat[64 + t] * invN - mean * mean;
        float A = gam[t] * rsqrtf(fmaxf(var, 0.f) + EPS_);
        AB[t] = A;
        AB[64 + t] = bet[t] - mean * A;
    }
    __syncthreads();
    float A = AB[lane];
    float B = AB[64 + lane];
    size_t cbase = (size_t)(lane >> 4) * N * 16 + (lane & 15);
    for (int i = blockIdx.x * 4 + ty; i < N; i += gridDim.x * 4) {
        float v = fmaxf(b2f(h[(size_t)i * 64 + lane]) * A + B, 0.f);
        float s = 0.f;
        for (int k = 0; k < 64; k++) s += __shfl(v, k) * Wsm[k * 64 + lane];
        s *= rsqrtf((float)(deg[i] + 1));
        y[cbase + (size_t)i * 16] = __float2bfloat16(s);
    }
}

// ---- Layer-1 gather, ONE CHANNEL CHUNK (16 ch, 3.2 MB: L2-resident) ----
// wave = 4 subwaves x 16 lanes; subwave handles one node.
__global__ __launch_bounds__(256) void k_gatherc(const bf16* y, const int* csr,
                                                 const int* start, const int* deg,
                                                 const float* bias, bf16* h,
                                                 float* stat, int N, int chunk) {
    __shared__ float sm[2][4][16];
    int t = threadIdx.x, lane = t & 63, ty = t >> 6;
    int sw = lane >> 4, cl = lane & 15;
    const bf16* yc = y + (size_t)chunk * N * 16;
    bf16* hc = h + (size_t)chunk * N * 16;
    float b = bias[chunk * 16 + cl];
    float sum = 0.f, sq = 0.f;
    int wid = blockIdx.x * 4 + ty;
    int stride = gridDim.x * 16;
    for (int i = wid * 4 + sw; i < N; i += stride) {
        int dg = deg[i], s0 = start[i];
        float acc = b2f(yc[(size_t)i * 16 + cl]);    // self-loop term
        int j = 0;
        while (j < dg) {
            int nch = dg - j;
            if (nch > 16) nch = 16;
            int idx = 0;
            if (cl < nch) idx = csr[s0 + j + cl];    // 16-wide coalesced prefetch
            int k = 0;
            for (; k + 8 <= nch; k += 8) {
                int ii[8];
                float a[8];
                #pragma unroll
                for (int u = 0; u < 8; u++) ii[u] = __shfl(idx, sw * 16 + k + u);
                #pragma unroll
                for (int u = 0; u < 8; u++) a[u] = b2f(yc[(size_t)ii[u] * 16 + cl]);
                acc += ((a[0] + a[1]) + (a[2] + a[3])) + ((a[4] + a[5]) + (a[6] + a[7]));
            }
            for (; k < nch; k++) {
                int s = __shfl(idx, sw * 16 + k);
                acc += b2f(yc[(size_t)s * 16 + cl]);
            }
            j += nch;
        }
        float v = acc * rsqrtf((float)(dg + 1)) + b;
        hc[(size_t)i * 16 + cl] = __float2bfloat16(v);
        sum += v; sq += v * v;
    }
    sum += __shfl_down(sum, 32); sq += __shfl_down(sq, 32);
    sum += __shfl_down(sum, 16); sq += __shfl_down(sq, 16);
    if (lane < 16) { sm[0][ty][lane] = sum; sm[1][ty][lane] = sq; }
    __syncthreads();
    if (t < 16) {
        atomicAdd(&stat[chunk * 16 + t],      sm[0][0][t] + sm[0][1][t] + sm[0][2][t] + sm[0][3][t]);
        atomicAdd(&stat[64 + chunk * 16 + t], sm[1][0][t] + sm[1][1][t] + sm[1][2][t] + sm[1][3][t]);
    }
}

// ---- Pool: BN1(affine)+ReLU fused; reads h CHUNK-MAJOR -----------------
__global__ __launch_bounds__(256) void k_pool(const bf16* h, const float* stat,
                                              const float* gam, const float* bet,
                                              const int* batch, float* pooled,
                                              float* cnt, float invN, int N) {
    int t = threadIdx.x;
    int lane = t & 63;
    float mean = stat[lane] * invN;
    float var = stat[64 + lane] * invN - mean * mean;
    float A = gam[lane] * rsqrtf(fmaxf(var, 0.f) + EPS_);
    float B = bet[lane] - mean * A;
    size_t cbase = (size_t)(lane >> 4) * N * 16 + (lane & 15);
    int w = (blockIdx.x * 256 + t) >> 6;
    int nw = (gridDim.x * 256) >> 6;
    int chunk = (N + nw - 1) / nw;
    int i0 = w * chunk;
    int i1 = i0 + chunk;
    if (i1 > N) i1 = N;
    if (i0 >= N) return;
    int curg = batch[i0];
    float acc = 0.f, c = 0.f;
    for (int i = i0; i < i1; i++) {
        int g = batch[i];
        if (g != curg) {
            atomicAdd(&pooled[(size_t)curg * 64 + lane], acc);
            if (lane == 0) atomicAdd(&cnt[curg], c);
            curg = g; acc = 0.f; c = 0.f;
        }
        acc += fmaxf(b2f(h[cbase + (size_t)i * 16]) * A + B, 0.f);
        c += 1.f;
    }
    atomicAdd(&pooled[(size_t)curg * 64 + lane], acc);
    if (lane == 0) atomicAdd(&cnt[curg], c);
}

// ---- Head --------------------------------------------------------------
__global__ __launch_bounds__(64) void k_head(const float* pooled_c, const float* cnt_c,
                                             const float* pooled_s, const float* cnt_s,
                                             const float* Wf1, const float* bf1_,
                                             const float* Wf2, const float* bf2_,
                                             float* out) {
    __shared__ float W1sm[128 * 64];
    __shared__ float W2sm[128];
    int t = threadIdx.x;  // blockDim = 64
    for (int i = t; i < 128 * 64; i += 64) W1sm[i] = Wf1[i];
    for (int i = t; i < 128; i += 64) W2sm[i] = Wf2[i];
    __syncthreads();
    float bb1 = bf1_[t];
    float b20 = bf2_[0];
    float b21 = bf2_[1];
    for (int g = blockIdx.x; g < G_; g += gridDim.x) {
        float ic = 1.f / fmaxf(cnt_c[g], 1.f);
        float is = 1.f / fmaxf(cnt_s[g], 1.f);
        float hc = pooled_c[(size_t)g * 64 + t] * ic;
        float hs = pooled_s[(size_t)g * 64 + t] * is;
        float s = bb1;
        for (int k = 0; k < 64; k++) s += __shfl(hc, k) * W1sm[k * 64 + t];
        for (int k = 0; k < 64; k++) s += __shfl(hs, k) * W1sm[(64 + k) * 64 + t];
        s = fmaxf(s, 0.f);
        float p0 = s * W2sm[t * 2 + 0];
        float p1 = s * W2sm[t * 2 + 1];
        for (int off = 32; off > 0; off >>= 1) {
            p0 += __shfl_down(p0, off);
            p1 += __shfl_down(p1, off);
        }
        if (t == 0) {
            out[g * 2 + 0] = p0 + b20;
            out[g * 2 + 1] = p1 + b21;
        }
    }
}

extern "C" void kernel_launch(void* const* d_in, const int* in_sizes, int n_in,
                              void* d_out, int out_size, void* d_ws, size_t ws_size,
                              hipStream_t stream) {
    float* out = (float*)d_out;

    if (n_in != 26 || in_sizes[0] != NC_ * 7 || in_sizes[1] != 2 * EC_ ||
        in_sizes[2] != NC_ || in_sizes[3] != NS_ * 7 || in_sizes[4] != 2 * ES_ ||
        in_sizes[5] != NS_ || out_size != G_ * 2) {
        k_fillout<<<(out_size + 255) / 256, 256, 0, stream>>>(out, 7777.0f, out_size);
        return;
    }
    if (ws_size < (size_t)WS_REQUIRED) {
        k_fillout<<<(out_size + 255) / 256, 256, 0, stream>>>(
            out, 1000.0f + (float)(ws_size >> 20), out_size);
        return;
    }

    const float* x_c     = (const float*)d_in[0];
    const int*   ei_c    = (const int*)d_in[1];
    const int*   batch_c = (const int*)d_in[2];
    const float* x_s     = (const float*)d_in[3];
    const int*   ei_s    = (const int*)d_in[4];
    const int*   batch_s = (const int*)d_in[5];
    const float* Wc0  = (const float*)d_in[6];
    const float* bc0  = (const float*)d_in[7];
    const float* gc0  = (const float*)d_in[8];
    const float* bec0 = (const float*)d_in[9];
    const float* Wc1  = (const float*)d_in[10];
    const float* bc1  = (const float*)d_in[11];
    const float* gc1  = (const float*)d_in[12];
    const float* bec1 = (const float*)d_in[13];
    const float* Ws0  = (const float*)d_in[14];
    const float* bs0  = (const float*)d_in[15];
    const float* gs0  = (const float*)d_in[16];
    const float* bes0 = (const float*)d_in[17];
    const float* Ws1  = (const float*)d_in[18];
    const float* bs1  = (const float*)d_in[19];
    const float* gs1  = (const float*)d_in[20];
    const float* bes1 = (const float*)d_in[21];
    const float* Wf1  = (const float*)d_in[22];
    const float* bf1_ = (const float*)d_in[23];
    const float* Wf2  = (const float*)d_in[24];
    const float* bf2_ = (const float*)d_in[25];

    // ---- workspace layout (4-byte words); total 39,748,624 bytes ----
    int* wsw = (int*)d_ws;
    size_t off = 0;
    float* stats_c  = (float*)(wsw + off); off += 256;   // [0..127] L0, [128..255] L1
    float* stats_s  = (float*)(wsw + off); off += 256;
    float* pooled_c = (float*)(wsw + off); off += (size_t)G_ * 64;
    float* pooled_s = (float*)(wsw + off); off += (size_t)G_ * 64;
    float* cnt_c    = (float*)(wsw + off); off += G_;
    float* cnt_s    = (float*)(wsw + off); off += G_;
    int*   bcnt_c   = wsw + off; off += NB_C;
    int*   bcnt_s   = wsw + off; off += NB_S;
    size_t zero_words = off;
    int*   bbase_c  = wsw + off; off += NB_C + 1;
    int*   bcur_c   = wsw + off; off += NB_C;
    int*   bbase_s  = wsw + off; off += NB_S + 1;
    int*   bcur_s   = wsw + off; off += NB_S;
    int*   deg      = wsw + off; off += NC_;          // shared by branches
    int*   start    = wsw + off; off += NC_;
    int*   csr      = wsw + off; off += EC_;
    int*   ebuf     = wsw + off; off += EC_;
    off = (off + 3) & ~(size_t)3;                     // 16 B align for uint4 loads
    bf16*  ybuf     = (bf16*)(wsw + off); off += (size_t)NC_ * 32;
    bf16*  hbuf     = (bf16*)(wsw + off); off += (size_t)NC_ * 32;
    bf16*  ubuf     = (bf16*)ybuf;   // u (NC*16 B) aliases ybuf; dead before gemm1 writes y

    k_zero<<<512, 256, 0, stream>>>(wsw, (int)zero_words);

    // ---- CSR prep (histograms + scans for both branches) ----
    k_bhist<<<256, 256, 0, stream>>>(ei_c + EC_, bcnt_c, EC_, NB_C);
    k_bhist<<<256, 256, 0, stream>>>(ei_s + ES_, bcnt_s, ES_, NB_S);
    k_bscan<<<1, 256, 0, stream>>>(bcnt_c, bbase_c, bcur_c, NB_C,
                                   bcnt_s, bbase_s, bcur_s, NB_S);

    // ---- chromo branch ----
    k_bin<<<391, 256, 0, stream>>>(ei_c, ei_c + EC_, bcur_c, ebuf, EC_, NB_C, 4096);
    k_build<<<NB_C, 256, 0, stream>>>(bbase_c, ebuf, x_c, ubuf, deg, start, csr, NC_);
    k_gather7<<<512, 256, 0, stream>>>(ubuf, csr, start, deg, Wc0, bc0, hbuf, stats_c, NC_);
    k_gemm1<<<1024, 256, 0, stream>>>(hbuf, Wc1, stats_c, gc0, bec0, deg, ybuf, 1.0f / NC_, NC_);
    for (int c = 0; c < 4; c++)
        k_gatherc<<<1024, 256, 0, stream>>>(ybuf, csr, start, deg, bc1, hbuf, stats_c + 128, NC_, c);
    k_pool<<<256, 256, 0, stream>>>(hbuf, stats_c + 128, gc1, bec1, batch_c, pooled_c, cnt_c, 1.0f / NC_, NC_);

    // ---- solvent branch (reuses ebuf/csr/deg/start/ybuf/hbuf) ----
    k_bin<<<391, 256, 0, stream>>>(ei_s, ei_s + ES_, bcur_s, ebuf, ES_, NB_S, 2048);
    k_build<<<NB_S, 256, 0, stream>>>(bbase_s, ebuf, x_s, ubuf, deg, start, csr, NS_);
    k_gather7<<<256, 256, 0, stream>>>(ubuf, csr, start, deg, Ws0, bs0, hbuf, stats_s, NS_);
    k_gemm1<<<1024, 256, 0, stream>>>(hbuf, Ws1, stats_s, gs0, bes0, deg, ybuf, 1.0f / NS_, NS_);
    for (int c = 0; c < 4; c++)
        k_gatherc<<<512, 256, 0, stream>>>(ybuf, csr, start, deg, bs1, hbuf, stats_s + 128, NS_, c);
    k_pool<<<256, 256, 0, stream>>>(hbuf, stats_s + 128, gs1, bes1, batch_s, pooled_s, cnt_s, 1.0f / NS_, NS_);

    // ---- head ----
    k_head<<<128, 64, 0, stream>>>(pooled_c, cnt_c, pooled_s, cnt_s, Wf1, bf1_, Wf2, bf2_, out);
}

// Round 11
// 537.822 us; speedup vs baseline: 1.3969x; 1.3969x over previous
//
#include <hip/hip_runtime.h>
#include <hip/hip_bf16.h>

typedef __hip_bfloat16 bf16;
typedef __attribute__((ext_vector_type(8))) short short8;
typedef __attribute__((ext_vector_type(4))) float f32x4;

#define NC_ 100000
#define EC_ 1600000
#define NS_ 50000
#define ES_ 800000
#define G_  1024
#define EPS_ 1e-5f

#define NB_C 782          // ceil(100000/128)
#define NB_S 391          // ceil(50000/128)
#define NBMAX 782
#define KSL 16            // LDS slots per bucket in k_bin

#define WS_REQUIRED 39752720ull

__device__ __forceinline__ float b2f(bf16 v) { return __bfloat162float(v); }

__device__ __forceinline__ unsigned short f2bfbits(float v) {
    bf16 b = __float2bfloat16(v);
    union { bf16 b; unsigned short u; } c; c.b = b; return c.u;
}

__device__ __forceinline__ void acc8(float* a, uint4 r) {
    a[0] += __uint_as_float(r.x << 16); a[1] += __uint_as_float(r.x & 0xffff0000u);
    a[2] += __uint_as_float(r.y << 16); a[3] += __uint_as_float(r.y & 0xffff0000u);
    a[4] += __uint_as_float(r.z << 16); a[5] += __uint_as_float(r.z & 0xffff0000u);
    a[6] += __uint_as_float(r.w << 16); a[7] += __uint_as_float(r.w & 0xffff0000u);
}

__global__ void DualGNN_31327491457689_kernel() {}

__global__ __launch_bounds__(256) void k_fillout(float* out, float val, int n) {
    int i = blockIdx.x * 256 + threadIdx.x;
    if (i < n) out[i] = val;
}

__global__ __launch_bounds__(256) void k_zero(int* p, int n) {
    int i = blockIdx.x * 256 + threadIdx.x;
    int stride = gridDim.x * 256;
    while (i < n) { p[i] = 0; i += stride; }
}

// ---- Phase A: bucket histogram (LDS-staged) ----------------------------
__global__ __launch_bounds__(256) void k_bhist(const int* dst, int* bcnt, int E, int NB) {
    __shared__ int h[NBMAX];
    int t = threadIdx.x;
    for (int i = t; i < NB; i += 256) h[i] = 0;
    __syncthreads();
    for (int e = blockIdx.x * 256 + t; e < E; e += gridDim.x * 256)
        atomicAdd(&h[dst[e] >> 7], 1);
    __syncthreads();
    for (int i = t; i < NB; i += 256) {
        int v = h[i];
        if (v) atomicAdd(&bcnt[i], v);
    }
}

// ---- Phase B: scan bucket counts (both branches, one block) ------------
__device__ void scan_one(const int* cnt, int* base, int* cur, int NB, int (*sc)[1024]) {
    int t = threadIdx.x;
    for (int i = t; i < 1024; i += 256) sc[0][i] = (i < NB) ? cnt[i] : 0;
    __syncthreads();
    int pin = 0;
    for (int off = 1; off < 1024; off <<= 1) {
        for (int i = t; i < 1024; i += 256) {
            int v = sc[pin][i];
            if (i >= off) v += sc[pin][i - off];
            sc[1 - pin][i] = v;
        }
        __syncthreads();
        pin ^= 1;
    }
    for (int i = t; i <= NB; i += 256) {
        int e = (i == 0) ? 0 : sc[pin][i - 1];
        base[i] = e;
        if (i < NB) cur[i] = e;
    }
    __syncthreads();
}

__global__ __launch_bounds__(256) void k_bscan(const int* cnt_c, int* base_c, int* cur_c, int NBc,
                                               const int* cnt_s, int* base_s, int* cur_s, int NBs) {
    __shared__ int sc[2][1024];
    scan_one(cnt_c, base_c, cur_c, NBc, sc);
    scan_one(cnt_s, base_s, cur_s, NBs, sc);
}

// ---- Phase C: bin packed edges into bucket-partitioned streams ---------
__global__ __launch_bounds__(256) void k_bin(const int* src, const int* dst, int* bcur,
                                             int* ebuf, int E, int NB, int CHUNK) {
    __shared__ int cnt[NBMAX];
    __shared__ int slot[NBMAX * KSL];
    int t = threadIdx.x;
    for (long long base = (long long)blockIdx.x * CHUNK; base < E;
         base += (long long)gridDim.x * CHUNK) {
        for (int i = t; i < NB; i += 256) cnt[i] = 0;
        __syncthreads();
        int e1 = (int)base + CHUNK;
        if (e1 > E) e1 = E;
        for (int e = (int)base + t; e < e1; e += 256) {
            int d = dst[e];
            int p = ((d & 127) << 24) | src[e];
            int b = d >> 7;
            int sl = atomicAdd(&cnt[b], 1);
            if (sl < KSL) slot[b * KSL + sl] = p;
            else { int gp = atomicAdd(&bcur[b], 1); ebuf[gp] = p; }
        }
        __syncthreads();
        for (int b = t; b < NB; b += 256) {
            int c = cnt[b];
            if (c > KSL) c = KSL;
            if (c > 0) {
                int gp = atomicAdd(&bcur[b], c);
                for (int k = 0; k < c; k++) ebuf[gp + k] = slot[b * KSL + k];
            }
        }
        __syncthreads();
    }
}

// ---- Phase D: per-bucket deg/start/csr build + fused layer-0 prep ------
__global__ __launch_bounds__(256) void k_build(const int* bbase, const int* ebuf,
                                               const float* x, bf16* u,
                                               int* deg, int* start, int* csr, int N) {
    __shared__ int lcnt[128], lofs[128], lcur[128];
    int b = blockIdx.x, t = threadIdx.x;
    int e0 = bbase[b], e1 = bbase[b + 1];
    int n0 = b << 7;
    if (t < 128) lcnt[t] = 0;
    __syncthreads();
    for (int e = e0 + t; e < e1; e += 256)
        atomicAdd(&lcnt[((unsigned)ebuf[e]) >> 24], 1);
    __syncthreads();
    if (t < 64) {
        int v0 = lcnt[2 * t], v1 = lcnt[2 * t + 1];
        int s = v0 + v1, incl = s;
        for (int off = 1; off < 64; off <<= 1) {
            int uu = __shfl_up(incl, off);
            if (t >= off) incl += uu;
        }
        int excl = incl - s;
        lofs[2 * t] = excl;
        lofs[2 * t + 1] = excl + v0;
    }
    __syncthreads();
    if (t < 128) {
        int node = n0 + t;
        if (node < N) {
            deg[node] = lcnt[t];
            start[node] = e0 + lofs[t];
            float d = rsqrtf((float)(lcnt[t] + 1));
            union __align__(16) Pack { bf16 hh[8]; uint4 v; } p;
            for (int k = 0; k < 7; k++) p.hh[k] = __float2bfloat16(x[node * 7 + k] * d);
            p.hh[7] = __float2bfloat16(0.f);
            ((uint4*)u)[node] = p.v;
        }
        lcur[t] = lofs[t];
    }
    __syncthreads();
    for (int e = e0 + t; e < e1; e += 256) {
        unsigned p = (unsigned)ebuf[e];
        int dl = p >> 24;
        int pos = atomicAdd(&lcur[dl], 1);
        csr[e0 + pos] = (int)(p & 0xFFFFFF);
    }
}

// ---- Layer 0 gather in rank-7 space + fused 7x64 GEMM + bias + stats ---
__global__ __launch_bounds__(256) void k_gather7(const bf16* u, const int* csr,
                                                 const int* start, const int* deg,
                                                 const float* W, const float* bias,
                                                 bf16* h, float* stat, int N) {
    __shared__ float Wsm[7 * 64];
    __shared__ float agg[256][9];
    __shared__ float sm[2][4][64];
    int t = threadIdx.x, lane = t & 63, ty = t >> 6;
    for (int i = t; i < 448; i += 256) Wsm[i] = W[i];
    float b = bias[lane];
    float sum = 0.f, sq = 0.f;
    const uint4* up = (const uint4*)u;
    for (int base = blockIdx.x * 256; base < N; base += gridDim.x * 256) {
        __syncthreads();
        int i = base + t;
        float a[8] = {0.f, 0.f, 0.f, 0.f, 0.f, 0.f, 0.f, 0.f};
        if (i < N) {
            int dg = deg[i], s0 = start[i];
            acc8(a, up[i]);
            int j = 0;
            for (; j + 4 <= dg; j += 4) {
                int i0 = csr[s0 + j], i1 = csr[s0 + j + 1];
                int i2 = csr[s0 + j + 2], i3 = csr[s0 + j + 3];
                uint4 r0 = up[i0], r1 = up[i1], r2 = up[i2], r3 = up[i3];
                acc8(a, r0); acc8(a, r1); acc8(a, r2); acc8(a, r3);
            }
            for (; j < dg; j++) acc8(a, up[csr[s0 + j]]);
            float di = rsqrtf((float)(dg + 1));
            for (int k = 0; k < 7; k++) a[k] *= di;
        }
        #pragma unroll
        for (int k = 0; k < 7; k++) agg[t][k] = a[k];
        __syncthreads();
        int mbase = base + ty * 64;
        for (int mm = 0; mm < 64; mm++) {
            int node = mbase + mm;
            if (node >= N) break;
            const float* ag = agg[ty * 64 + mm];
            float s = b;
            #pragma unroll
            for (int k = 0; k < 7; k++) s += ag[k] * Wsm[k * 64 + lane];
            h[(size_t)node * 64 + lane] = __float2bfloat16(s);
            sum += s; sq += s * s;
        }
    }
    sm[0][ty][lane] = sum;
    sm[1][ty][lane] = sq;
    __syncthreads();
    if (ty == 0) {
        atomicAdd(&stat[lane],      sm[0][0][lane] + sm[0][1][lane] + sm[0][2][lane] + sm[0][3][lane]);
        atomicAdd(&stat[64 + lane], sm[1][0][lane] + sm[1][1][lane] + sm[1][2][lane] + sm[1][3][lane]);
    }
}

// ---- Layer 1 GEMM via MFMA: y = dinv * relu(bn(h)) @ W1 ----------------
// Wave does a 64-node x 64-ch tile: 4mt x 4nt x 2kt mfma_f32_16x16x32_bf16.
// A[m=lane&15][k=quad*8+j]; B[k=quad*8+j][n=lane&15]; D col=lane&15, row=quad*4+r.
__global__ __launch_bounds__(256) void k_gemm1(const bf16* h, const float* W,
                                               const float* stat, const float* gam,
                                               const float* bet, const int* deg,
                                               bf16* y, float invN, int N) {
    __shared__ short Wt[64][72];     // W1^T as bf16 bits (row n, col k), padded
    __shared__ float AB[128];
    int t = threadIdx.x, lane = t & 63, ty = t >> 6;
    for (int i = t; i < 4096; i += 256) {
        int k = i >> 6, n = i & 63;
        Wt[n][k] = (short)f2bfbits(W[i]);
    }
    if (t < 64) {
        float mean = stat[t] * invN;
        float var = stat[64 + t] * invN - mean * mean;
        float A = gam[t] * rsqrtf(fmaxf(var, 0.f) + EPS_);
        AB[t] = A;
        AB[64 + t] = bet[t] - mean * A;
    }
    __syncthreads();
    int quad = lane >> 4, l16 = lane & 15;
    short8 Bf[2][4];                 // loop-invariant B fragments
    #pragma unroll
    for (int kt = 0; kt < 2; kt++)
        #pragma unroll
        for (int nt = 0; nt < 4; nt++) {
            int n = nt * 16 + l16, k0 = kt * 32 + quad * 8;
            Bf[kt][nt] = *(const short8*)&Wt[n][k0];
        }
    int ntile = (N + 63) >> 6;
    for (int tile = blockIdx.x * 4 + ty; tile < ntile; tile += gridDim.x * 4) {
        int base = tile << 6;
        f32x4 acc[4][4];
        #pragma unroll
        for (int a = 0; a < 4; a++)
            #pragma unroll
            for (int b = 0; b < 4; b++) acc[a][b] = (f32x4){0.f, 0.f, 0.f, 0.f};
        #pragma unroll
        for (int kt = 0; kt < 2; kt++) {
            int k0 = kt * 32 + quad * 8;
            float Ak[8], Bk[8];
            #pragma unroll
            for (int j = 0; j < 8; j++) { Ak[j] = AB[k0 + j]; Bk[j] = AB[64 + k0 + j]; }
            #pragma unroll
            for (int mt = 0; mt < 4; mt++) {
                int node = base + mt * 16 + l16;     // may overread tail: ws padded
                uint4 raw = *(const uint4*)(h + (size_t)node * 64 + k0);
                unsigned rr[4] = {raw.x, raw.y, raw.z, raw.w};
                short8 af;
                #pragma unroll
                for (int j = 0; j < 8; j++) {
                    unsigned bits = (j & 1) ? (rr[j >> 1] & 0xffff0000u)
                                            : (rr[j >> 1] << 16);
                    float v = __uint_as_float(bits);
                    v = fmaxf(v * Ak[j] + Bk[j], 0.f);
                    af[j] = (short)f2bfbits(v);
                }
                #pragma unroll
                for (int nt = 0; nt < 4; nt++)
                    acc[mt][nt] = __builtin_amdgcn_mfma_f32_16x16x32_bf16(
                        af, Bf[kt][nt], acc[mt][nt], 0, 0, 0);
            }
        }
        #pragma unroll
        for (int mt = 0; mt < 4; mt++)
            #pragma unroll
            for (int r = 0; r < 4; r++) {
                int node = base + mt * 16 + quad * 4 + r;
                if (node < N) {
                    float dinv = rsqrtf((float)(deg[node] + 1));
                    #pragma unroll
                    for (int nt = 0; nt < 4; nt++)
                        y[(size_t)node * 64 + nt * 16 + l16] =
                            __float2bfloat16(acc[mt][nt][r] * dinv);
                }
            }
    }
}

// ---- Layer-1 gather: 64-index coalesced prefetch + 8 row loads in flight
__global__ __launch_bounds__(256) void k_gather(const bf16* y, const int* csr,
                                                const int* start, const int* deg,
                                                const float* bias, bf16* h,
                                                float* stat, int N) {
    __shared__ float sm[2][4][64];
    int t = threadIdx.x;
    int lane = t & 63;
    int ty = t >> 6;
    float b = bias[lane];
    float sum = 0.f, sq = 0.f;
    for (int i = blockIdx.x * 4 + ty; i < N; i += gridDim.x * 4) {
        int dg = deg[i];
        int s0 = start[i];
        float acc = b2f(y[(size_t)i * 64 + lane]);
        int j = 0;
        while (j < dg) {
            int nchunk = dg - j;
            if (nchunk > 64) nchunk = 64;
            int idx = 0;
            if (lane < nchunk) idx = csr[s0 + j + lane];
            int k = 0;
            for (; k + 8 <= nchunk; k += 8) {
                int i0 = __shfl(idx, k + 0);
                int i1 = __shfl(idx, k + 1);
                int i2 = __shfl(idx, k + 2);
                int i3 = __shfl(idx, k + 3);
                int i4 = __shfl(idx, k + 4);
                int i5 = __shfl(idx, k + 5);
                int i6 = __shfl(idx, k + 6);
                int i7 = __shfl(idx, k + 7);
                float a0 = b2f(y[(size_t)i0 * 64 + lane]);
                float a1 = b2f(y[(size_t)i1 * 64 + lane]);
                float a2 = b2f(y[(size_t)i2 * 64 + lane]);
                float a3 = b2f(y[(size_t)i3 * 64 + lane]);
                float a4 = b2f(y[(size_t)i4 * 64 + lane]);
                float a5 = b2f(y[(size_t)i5 * 64 + lane]);
                float a6 = b2f(y[(size_t)i6 * 64 + lane]);
                float a7 = b2f(y[(size_t)i7 * 64 + lane]);
                acc += ((a0 + a1) + (a2 + a3)) + ((a4 + a5) + (a6 + a7));
            }
            for (; k < nchunk; k++) {
                int s = __shfl(idx, k);
                acc += b2f(y[(size_t)s * 64 + lane]);
            }
            j += nchunk;
        }
        float v = acc * rsqrtf((float)(dg + 1)) + b;
        h[(size_t)i * 64 + lane] = __float2bfloat16(v);
        sum += v; sq += v * v;
    }
    sm[0][ty][lane] = sum;
    sm[1][ty][lane] = sq;
    __syncthreads();
    if (ty == 0) {
        atomicAdd(&stat[lane],      sm[0][0][lane] + sm[0][1][lane] + sm[0][2][lane] + sm[0][3][lane]);
        atomicAdd(&stat[64 + lane], sm[1][0][lane] + sm[1][1][lane] + sm[1][2][lane] + sm[1][3][lane]);
    }
}

// ---- Pool: BN1(affine)+ReLU fused, run-length pre-agg (batch sorted) ---
__global__ __launch_bounds__(256) void k_pool(const bf16* h, const float* stat,
                                              const float* gam, const float* bet,
                                              const int* batch, float* pooled,
                                              float* cnt, float invN, int N) {
    int t = threadIdx.x;
    int lane = t & 63;
    float mean = stat[lane] * invN;
    float var = stat[64 + lane] * invN - mean * mean;
    float A = gam[lane] * rsqrtf(fmaxf(var, 0.f) + EPS_);
    float B = bet[lane] - mean * A;
    int w = (blockIdx.x * 256 + t) >> 6;
    int nw = (gridDim.x * 256) >> 6;
    int chunk = (N + nw - 1) / nw;
    int i0 = w * chunk;
    int i1 = i0 + chunk;
    if (i1 > N) i1 = N;
    if (i0 >= N) return;
    int curg = batch[i0];
    float acc = 0.f, c = 0.f;
    for (int i = i0; i < i1; i++) {
        int g = batch[i];
        if (g != curg) {
            atomicAdd(&pooled[(size_t)curg * 64 + lane], acc);
            if (lane == 0) atomicAdd(&cnt[curg], c);
            curg = g; acc = 0.f; c = 0.f;
        }
        acc += fmaxf(b2f(h[(size_t)i * 64 + lane]) * A + B, 0.f);
        c += 1.f;
    }
    atomicAdd(&pooled[(size_t)curg * 64 + lane], acc);
    if (lane == 0) atomicAdd(&cnt[curg], c);
}

// ---- Head --------------------------------------------------------------
__global__ __launch_bounds__(64) void k_head(const float* pooled_c, const float* cnt_c,
                                             const float* pooled_s, const float* cnt_s,
                                             const float* Wf1, const float* bf1_,
                                             const float* Wf2, const float* bf2_,
                                             float* out) {
    __shared__ float W1sm[128 * 64];
    __shared__ float W2sm[128];
    int t = threadIdx.x;  // blockDim = 64
    for (int i = t; i < 128 * 64; i += 64) W1sm[i] = Wf1[i];
    for (int i = t; i < 128; i += 64) W2sm[i] = Wf2[i];
    __syncthreads();
    float bb1 = bf1_[t];
    float b20 = bf2_[0];
    float b21 = bf2_[1];
    for (int g = blockIdx.x; g < G_; g += gridDim.x) {
        float ic = 1.f / fmaxf(cnt_c[g], 1.f);
        float is = 1.f / fmaxf(cnt_s[g], 1.f);
        float hc = pooled_c[(size_t)g * 64 + t] * ic;
        float hs = pooled_s[(size_t)g * 64 + t] * is;
        float s = bb1;
        for (int k = 0; k < 64; k++) s += __shfl(hc, k) * W1sm[k * 64 + t];
        for (int k = 0; k < 64; k++) s += __shfl(hs, k) * W1sm[(64 + k) * 64 + t];
        s = fmaxf(s, 0.f);
        float p0 = s * W2sm[t * 2 + 0];
        float p1 = s * W2sm[t * 2 + 1];
        for (int off = 32; off > 0; off >>= 1) {
            p0 += __shfl_down(p0, off);
            p1 += __shfl_down(p1, off);
        }
        if (t == 0) {
            out[g * 2 + 0] = p0 + b20;
            out[g * 2 + 1] = p1 + b21;
        }
    }
}

extern "C" void kernel_launch(void* const* d_in, const int* in_sizes, int n_in,
                              void* d_out, int out_size, void* d_ws, size_t ws_size,
                              hipStream_t stream) {
    float* out = (float*)d_out;

    if (n_in != 26 || in_sizes[0] != NC_ * 7 || in_sizes[1] != 2 * EC_ ||
        in_sizes[2] != NC_ || in_sizes[3] != NS_ * 7 || in_sizes[4] != 2 * ES_ ||
        in_sizes[5] != NS_ || out_size != G_ * 2) {
        k_fillout<<<(out_size + 255) / 256, 256, 0, stream>>>(out, 7777.0f, out_size);
        return;
    }
    if (ws_size < (size_t)WS_REQUIRED) {
        k_fillout<<<(out_size + 255) / 256, 256, 0, stream>>>(
            out, 1000.0f + (float)(ws_size >> 20), out_size);
        return;
    }

    const float* x_c     = (const float*)d_in[0];
    const int*   ei_c    = (const int*)d_in[1];
    const int*   batch_c = (const int*)d_in[2];
    const float* x_s     = (const float*)d_in[3];
    const int*   ei_s    = (const int*)d_in[4];
    const int*   batch_s = (const int*)d_in[5];
    const float* Wc0  = (const float*)d_in[6];
    const float* bc0  = (const float*)d_in[7];
    const float* gc0  = (const float*)d_in[8];
    const float* bec0 = (const float*)d_in[9];
    const float* Wc1  = (const float*)d_in[10];
    const float* bc1  = (const float*)d_in[11];
    const float* gc1  = (const float*)d_in[12];
    const float* bec1 = (const float*)d_in[13];
    const float* Ws0  = (const float*)d_in[14];
    const float* bs0  = (const float*)d_in[15];
    const float* gs0  = (const float*)d_in[16];
    const float* bes0 = (const float*)d_in[17];
    const float* Ws1  = (const float*)d_in[18];
    const float* bs1  = (const float*)d_in[19];
    const float* gs1  = (const float*)d_in[20];
    const float* bes1 = (const float*)d_in[21];
    const float* Wf1  = (const float*)d_in[22];
    const float* bf1_ = (const float*)d_in[23];
    const float* Wf2  = (const float*)d_in[24];
    const float* bf2_ = (const float*)d_in[25];

    // ---- workspace layout (4-byte words) ----
    int* wsw = (int*)d_ws;
    size_t off = 0;
    float* stats_c  = (float*)(wsw + off); off += 256;
    float* stats_s  = (float*)(wsw + off); off += 256;
    float* pooled_c = (float*)(wsw + off); off += (size_t)G_ * 64;
    float* pooled_s = (float*)(wsw + off); off += (size_t)G_ * 64;
    float* cnt_c    = (float*)(wsw + off); off += G_;
    float* cnt_s    = (float*)(wsw + off); off += G_;
    int*   bcnt_c   = wsw + off; off += NB_C;
    int*   bcnt_s   = wsw + off; off += NB_S;
    size_t zero_words = off;
    int*   bbase_c  = wsw + off; off += NB_C + 1;
    int*   bcur_c   = wsw + off; off += NB_C;
    int*   bbase_s  = wsw + off; off += NB_S + 1;
    int*   bcur_s   = wsw + off; off += NB_S;
    int*   deg      = wsw + off; off += NC_;
    int*   start    = wsw + off; off += NC_;
    int*   csr      = wsw + off; off += EC_;
    int*   ebuf     = wsw + off; off += EC_;
    off = (off + 3) & ~(size_t)3;
    bf16*  ybuf     = (bf16*)(wsw + off); off += (size_t)NC_ * 32;
    bf16*  hbuf     = (bf16*)(wsw + off); off += (size_t)NC_ * 32;
    off += 1024;   // tail pad: k_gemm1 last-tile overread
    bf16*  ubuf     = (bf16*)ybuf;   // u aliases ybuf; dead before gemm1 writes y

    k_zero<<<512, 256, 0, stream>>>(wsw, (int)zero_words);

    // ---- CSR prep ----
    k_bhist<<<256, 256, 0, stream>>>(ei_c + EC_, bcnt_c, EC_, NB_C);
    k_bhist<<<256, 256, 0, stream>>>(ei_s + ES_, bcnt_s, ES_, NB_S);
    k_bscan<<<1, 256, 0, stream>>>(bcnt_c, bbase_c, bcur_c, NB_C,
                                   bcnt_s, bbase_s, bcur_s, NB_S);

    // ---- chromo branch ----
    k_bin<<<391, 256, 0, stream>>>(ei_c, ei_c + EC_, bcur_c, ebuf, EC_, NB_C, 4096);
    k_build<<<NB_C, 256, 0, stream>>>(bbase_c, ebuf, x_c, ubuf, deg, start, csr, NC_);
    k_gather7<<<512, 256, 0, stream>>>(ubuf, csr, start, deg, Wc0, bc0, hbuf, stats_c, NC_);
    k_gemm1<<<512, 256, 0, stream>>>(hbuf, Wc1, stats_c, gc0, bec0, deg, ybuf, 1.0f / NC_, NC_);
    k_gather<<<1024, 256, 0, stream>>>(ybuf, csr, start, deg, bc1, hbuf, stats_c + 128, NC_);
    k_pool<<<256, 256, 0, stream>>>(hbuf, stats_c + 128, gc1, bec1, batch_c, pooled_c, cnt_c, 1.0f / NC_, NC_);

    // ---- solvent branch ----
    k_bin<<<391, 256, 0, stream>>>(ei_s, ei_s + ES_, bcur_s, ebuf, ES_, NB_S, 2048);
    k_build<<<NB_S, 256, 0, stream>>>(bbase_s, ebuf, x_s, ubuf, deg, start, csr, NS_);
    k_gather7<<<256, 256, 0, stream>>>(ubuf, csr, start, deg, Ws0, bs0, hbuf, stats_s, NS_);
    k_gemm1<<<512, 256, 0, stream>>>(hbuf, Ws1, stats_s, gs0, bes0, deg, ybuf, 1.0f / NS_, NS_);
    k_gather<<<1024, 256, 0, stream>>>(ybuf, csr, start, deg, bs1, hbuf, stats_s + 128, NS_);
    k_pool<<<256, 256, 0, stream>>>(hbuf, stats_s + 128, gs1, bes1, batch_s, pooled_s, cnt_s, 1.0f / NS_, NS_);

    // ---- head ----
    k_head<<<128, 64, 0, stream>>>(pooled_c, cnt_c, pooled_s, cnt_s, Wf1, bf1_, Wf2, bf2_, out);
}

// Round 12
// 477.258 us; speedup vs baseline: 1.5741x; 1.1269x over previous
//
#include <hip/hip_runtime.h>
#include <hip/hip_bf16.h>

typedef __hip_bfloat16 bf16;
typedef __attribute__((ext_vector_type(8))) short short8;
typedef __attribute__((ext_vector_type(4))) float f32x4;

#define NC_ 100000
#define EC_ 1600000
#define NS_ 50000
#define ES_ 800000
#define G_  1024
#define EPS_ 1e-5f

#define NB_C 782          // ceil(100000/128)
#define NB_S 391          // ceil(50000/128)
#define NBMAX 782
#define KSL 16            // LDS slots per bucket in k_bin

#define WS_REQUIRED 39752720ull

__device__ __forceinline__ float b2f(bf16 v) { return __bfloat162float(v); }

__device__ __forceinline__ unsigned short f2bfbits(float v) {
    bf16 b = __float2bfloat16(v);
    union { bf16 b; unsigned short u; } c; c.b = b; return c.u;
}

__device__ __forceinline__ void acc8(float* a, uint4 r) {
    a[0] += __uint_as_float(r.x << 16); a[1] += __uint_as_float(r.x & 0xffff0000u);
    a[2] += __uint_as_float(r.y << 16); a[3] += __uint_as_float(r.y & 0xffff0000u);
    a[4] += __uint_as_float(r.z << 16); a[5] += __uint_as_float(r.z & 0xffff0000u);
    a[6] += __uint_as_float(r.w << 16); a[7] += __uint_as_float(r.w & 0xffff0000u);
}

__global__ void DualGNN_31327491457689_kernel() {}

__global__ __launch_bounds__(256) void k_fillout(float* out, float val, int n) {
    int i = blockIdx.x * 256 + threadIdx.x;
    if (i < n) out[i] = val;
}

__global__ __launch_bounds__(256) void k_zero(int* p, int n) {
    int i = blockIdx.x * 256 + threadIdx.x;
    int stride = gridDim.x * 256;
    while (i < n) { p[i] = 0; i += stride; }
}

// ---- Phase A: bucket histogram (LDS-staged) ----------------------------
__global__ __launch_bounds__(256) void k_bhist(const int* dst, int* bcnt, int E, int NB) {
    __shared__ int h[NBMAX];
    int t = threadIdx.x;
    for (int i = t; i < NB; i += 256) h[i] = 0;
    __syncthreads();
    for (int e = blockIdx.x * 256 + t; e < E; e += gridDim.x * 256)
        atomicAdd(&h[dst[e] >> 7], 1);
    __syncthreads();
    for (int i = t; i < NB; i += 256) {
        int v = h[i];
        if (v) atomicAdd(&bcnt[i], v);
    }
}

// ---- Phase B: scan bucket counts (both branches, one block) ------------
__device__ void scan_one(const int* cnt, int* base, int* cur, int NB, int (*sc)[1024]) {
    int t = threadIdx.x;
    for (int i = t; i < 1024; i += 256) sc[0][i] = (i < NB) ? cnt[i] : 0;
    __syncthreads();
    int pin = 0;
    for (int off = 1; off < 1024; off <<= 1) {
        for (int i = t; i < 1024; i += 256) {
            int v = sc[pin][i];
            if (i >= off) v += sc[pin][i - off];
            sc[1 - pin][i] = v;
        }
        __syncthreads();
        pin ^= 1;
    }
    for (int i = t; i <= NB; i += 256) {
        int e = (i == 0) ? 0 : sc[pin][i - 1];
        base[i] = e;
        if (i < NB) cur[i] = e;
    }
    __syncthreads();
}

__global__ __launch_bounds__(256) void k_bscan(const int* cnt_c, int* base_c, int* cur_c, int NBc,
                                               const int* cnt_s, int* base_s, int* cur_s, int NBs) {
    __shared__ int sc[2][1024];
    scan_one(cnt_c, base_c, cur_c, NBc, sc);
    scan_one(cnt_s, base_s, cur_s, NBs, sc);
}

// ---- Phase C: bin packed edges into bucket-partitioned streams ---------
__global__ __launch_bounds__(256) void k_bin(const int* src, const int* dst, int* bcur,
                                             int* ebuf, int E, int NB, int CHUNK) {
    __shared__ int cnt[NBMAX];
    __shared__ int slot[NBMAX * KSL];
    int t = threadIdx.x;
    for (long long base = (long long)blockIdx.x * CHUNK; base < E;
         base += (long long)gridDim.x * CHUNK) {
        for (int i = t; i < NB; i += 256) cnt[i] = 0;
        __syncthreads();
        int e1 = (int)base + CHUNK;
        if (e1 > E) e1 = E;
        for (int e = (int)base + t; e < e1; e += 256) {
            int d = dst[e];
            int p = ((d & 127) << 24) | src[e];
            int b = d >> 7;
            int sl = atomicAdd(&cnt[b], 1);
            if (sl < KSL) slot[b * KSL + sl] = p;
            else { int gp = atomicAdd(&bcur[b], 1); ebuf[gp] = p; }
        }
        __syncthreads();
        for (int b = t; b < NB; b += 256) {
            int c = cnt[b];
            if (c > KSL) c = KSL;
            if (c > 0) {
                int gp = atomicAdd(&bcur[b], c);
                for (int k = 0; k < c; k++) ebuf[gp + k] = slot[b * KSL + k];
            }
        }
        __syncthreads();
    }
}

// ---- Phase D: per-bucket deg/start/csr build + fused layer-0 prep ------
__global__ __launch_bounds__(256) void k_build(const int* bbase, const int* ebuf,
                                               const float* x, bf16* u,
                                               int* deg, int* start, int* csr, int N) {
    __shared__ int lcnt[128], lofs[128], lcur[128];
    int b = blockIdx.x, t = threadIdx.x;
    int e0 = bbase[b], e1 = bbase[b + 1];
    int n0 = b << 7;
    if (t < 128) lcnt[t] = 0;
    __syncthreads();
    for (int e = e0 + t; e < e1; e += 256)
        atomicAdd(&lcnt[((unsigned)ebuf[e]) >> 24], 1);
    __syncthreads();
    if (t < 64) {
        int v0 = lcnt[2 * t], v1 = lcnt[2 * t + 1];
        int s = v0 + v1, incl = s;
        for (int off = 1; off < 64; off <<= 1) {
            int uu = __shfl_up(incl, off);
            if (t >= off) incl += uu;
        }
        int excl = incl - s;
        lofs[2 * t] = excl;
        lofs[2 * t + 1] = excl + v0;
    }
    __syncthreads();
    if (t < 128) {
        int node = n0 + t;
        if (node < N) {
            deg[node] = lcnt[t];
            start[node] = e0 + lofs[t];
            float d = rsqrtf((float)(lcnt[t] + 1));
            union __align__(16) Pack { bf16 hh[8]; uint4 v; } p;
            for (int k = 0; k < 7; k++) p.hh[k] = __float2bfloat16(x[node * 7 + k] * d);
            p.hh[7] = __float2bfloat16(0.f);
            ((uint4*)u)[node] = p.v;
        }
        lcur[t] = lofs[t];
    }
    __syncthreads();
    for (int e = e0 + t; e < e1; e += 256) {
        unsigned p = (unsigned)ebuf[e];
        int dl = p >> 24;
        int pos = atomicAdd(&lcur[dl], 1);
        csr[e0 + pos] = (int)(p & 0xFFFFFF);
    }
}

// ---- Layer 0 gather in rank-7 space + fused 7x64 GEMM + bias + stats ---
__global__ __launch_bounds__(256) void k_gather7(const bf16* u, const int* csr,
                                                 const int* start, const int* deg,
                                                 const float* W, const float* bias,
                                                 bf16* h, float* stat, int N) {
    __shared__ float Wsm[7 * 64];
    __shared__ float agg[256][9];
    __shared__ float sm[2][4][64];
    int t = threadIdx.x, lane = t & 63, ty = t >> 6;
    for (int i = t; i < 448; i += 256) Wsm[i] = W[i];
    float b = bias[lane];
    float sum = 0.f, sq = 0.f;
    const uint4* up = (const uint4*)u;
    for (int base = blockIdx.x * 256; base < N; base += gridDim.x * 256) {
        __syncthreads();
        int i = base + t;
        float a[8] = {0.f, 0.f, 0.f, 0.f, 0.f, 0.f, 0.f, 0.f};
        if (i < N) {
            int dg = deg[i], s0 = start[i];
            acc8(a, up[i]);
            int j = 0;
            for (; j + 4 <= dg; j += 4) {
                int i0 = csr[s0 + j], i1 = csr[s0 + j + 1];
                int i2 = csr[s0 + j + 2], i3 = csr[s0 + j + 3];
                uint4 r0 = up[i0], r1 = up[i1], r2 = up[i2], r3 = up[i3];
                acc8(a, r0); acc8(a, r1); acc8(a, r2); acc8(a, r3);
            }
            for (; j < dg; j++) acc8(a, up[csr[s0 + j]]);
            float di = rsqrtf((float)(dg + 1));
            for (int k = 0; k < 7; k++) a[k] *= di;
        }
        #pragma unroll
        for (int k = 0; k < 7; k++) agg[t][k] = a[k];
        __syncthreads();
        int mbase = base + ty * 64;
        for (int mm = 0; mm < 64; mm++) {
            int node = mbase + mm;
            if (node >= N) break;
            const float* ag = agg[ty * 64 + mm];
            float s = b;
            #pragma unroll
            for (int k = 0; k < 7; k++) s += ag[k] * Wsm[k * 64 + lane];
            h[(size_t)node * 64 + lane] = __float2bfloat16(s);
            sum += s; sq += s * s;
        }
    }
    sm[0][ty][lane] = sum;
    sm[1][ty][lane] = sq;
    __syncthreads();
    if (ty == 0) {
        atomicAdd(&stat[lane],      sm[0][0][lane] + sm[0][1][lane] + sm[0][2][lane] + sm[0][3][lane]);
        atomicAdd(&stat[64 + lane], sm[1][0][lane] + sm[1][1][lane] + sm[1][2][lane] + sm[1][3][lane]);
    }
}

// ---- Layer 1 GEMM via MFMA: y = dinv * relu(bn(h)) @ W1 ----------------
// Reads h row-major; writes y PLANE-MAJOR: y[(c>>3)*N*8 + node*8 + (c&7)].
__global__ __launch_bounds__(256) void k_gemm1(const bf16* h, const float* W,
                                               const float* stat, const float* gam,
                                               const float* bet, const int* deg,
                                               bf16* y, float invN, int N) {
    __shared__ short Wt[64][72];     // W1^T as bf16 bits (row n, col k), padded
    __shared__ float AB[128];
    int t = threadIdx.x, lane = t & 63, ty = t >> 6;
    for (int i = t; i < 4096; i += 256) {
        int k = i >> 6, n = i & 63;
        Wt[n][k] = (short)f2bfbits(W[i]);
    }
    if (t < 64) {
        float mean = stat[t] * invN;
        float var = stat[64 + t] * invN - mean * mean;
        float A = gam[t] * rsqrtf(fmaxf(var, 0.f) + EPS_);
        AB[t] = A;
        AB[64 + t] = bet[t] - mean * A;
    }
    __syncthreads();
    int quad = lane >> 4, l16 = lane & 15;
    short8 Bf[2][4];                 // loop-invariant B fragments
    #pragma unroll
    for (int kt = 0; kt < 2; kt++)
        #pragma unroll
        for (int nt = 0; nt < 4; nt++) {
            int n = nt * 16 + l16, k0 = kt * 32 + quad * 8;
            Bf[kt][nt] = *(const short8*)&Wt[n][k0];
        }
    int ntile = (N + 63) >> 6;
    for (int tile = blockIdx.x * 4 + ty; tile < ntile; tile += gridDim.x * 4) {
        int base = tile << 6;
        f32x4 acc[4][4];
        #pragma unroll
        for (int a = 0; a < 4; a++)
            #pragma unroll
            for (int b = 0; b < 4; b++) acc[a][b] = (f32x4){0.f, 0.f, 0.f, 0.f};
        #pragma unroll
        for (int kt = 0; kt < 2; kt++) {
            int k0 = kt * 32 + quad * 8;
            float Ak[8], Bk[8];
            #pragma unroll
            for (int j = 0; j < 8; j++) { Ak[j] = AB[k0 + j]; Bk[j] = AB[64 + k0 + j]; }
            #pragma unroll
            for (int mt = 0; mt < 4; mt++) {
                int node = base + mt * 16 + l16;     // may overread tail: ws padded
                uint4 raw = *(const uint4*)(h + (size_t)node * 64 + k0);
                unsigned rr[4] = {raw.x, raw.y, raw.z, raw.w};
                short8 af;
                #pragma unroll
                for (int j = 0; j < 8; j++) {
                    unsigned bits = (j & 1) ? (rr[j >> 1] & 0xffff0000u)
                                            : (rr[j >> 1] << 16);
                    float v = __uint_as_float(bits);
                    v = fmaxf(v * Ak[j] + Bk[j], 0.f);
                    af[j] = (short)f2bfbits(v);
                }
                #pragma unroll
                for (int nt = 0; nt < 4; nt++)
                    acc[mt][nt] = __builtin_amdgcn_mfma_f32_16x16x32_bf16(
                        af, Bf[kt][nt], acc[mt][nt], 0, 0, 0);
            }
        }
        #pragma unroll
        for (int mt = 0; mt < 4; mt++)
            #pragma unroll
            for (int r = 0; r < 4; r++) {
                int node = base + mt * 16 + quad * 4 + r;
                if (node < N) {
                    float dinv = rsqrtf((float)(deg[node] + 1));
                    #pragma unroll
                    for (int nt = 0; nt < 4; nt++) {
                        int c = nt * 16 + l16;
                        y[((size_t)(c >> 3) * N + node) * 8 + (c & 7)] =
                            __float2bfloat16(acc[mt][nt][r] * dinv);
                    }
                }
            }
    }
}

// ---- Layer-1 gather: 8-channel planes, XCD-pinned via blockIdx&7 -------
// y/h layout: [plane][node][8ch] bf16 (16 B rows, plane = 1.6MB -> L2-resident)
__global__ __launch_bounds__(256) void k_gather8(const bf16* y, const int* csr,
                                                 const int* start, const int* deg,
                                                 const float* bias, bf16* h,
                                                 float* stat, int N) {
    __shared__ float sms[4][2][8];
    int t = threadIdx.x, lane = t & 63, ty = t >> 6;
    int plane = blockIdx.x & 7;
    int grp = blockIdx.x >> 3;
    int ngrp = gridDim.x >> 3;
    const uint4* yp = (const uint4*)y + (size_t)plane * N;
    uint4* hp = (uint4*)h + (size_t)plane * N;
    float b[8];
    #pragma unroll
    for (int k = 0; k < 8; k++) b[k] = bias[plane * 8 + k];
    float sum[8] = {0.f, 0.f, 0.f, 0.f, 0.f, 0.f, 0.f, 0.f};
    float sq[8]  = {0.f, 0.f, 0.f, 0.f, 0.f, 0.f, 0.f, 0.f};
    for (int i = grp * 256 + t; i < N; i += ngrp * 256) {
        int dg = deg[i], s0 = start[i];
        float a[8] = {0.f, 0.f, 0.f, 0.f, 0.f, 0.f, 0.f, 0.f};
        acc8(a, yp[i]);                  // self-loop term
        int j = 0;
        for (; j + 4 <= dg; j += 4) {
            int i0 = csr[s0 + j], i1 = csr[s0 + j + 1];
            int i2 = csr[s0 + j + 2], i3 = csr[s0 + j + 3];
            uint4 r0 = yp[i0], r1 = yp[i1], r2 = yp[i2], r3 = yp[i3];
            acc8(a, r0); acc8(a, r1); acc8(a, r2); acc8(a, r3);
        }
        for (; j < dg; j++) acc8(a, yp[csr[s0 + j]]);
        float di = rsqrtf((float)(dg + 1));
        union __align__(16) Pack { bf16 hh[8]; uint4 v; } p;
        #pragma unroll
        for (int k = 0; k < 8; k++) {
            float v = a[k] * di + b[k];
            p.hh[k] = __float2bfloat16(v);
            sum[k] += v; sq[k] += v * v;
        }
        hp[i] = p.v;
    }
    #pragma unroll
    for (int k = 0; k < 8; k++) {
        float s1 = sum[k], s2 = sq[k];
        for (int off = 32; off > 0; off >>= 1) {
            s1 += __shfl_down(s1, off);
            s2 += __shfl_down(s2, off);
        }
        if (lane == 0) { sms[ty][0][k] = s1; sms[ty][1][k] = s2; }
    }
    __syncthreads();
    if (t < 8)
        atomicAdd(&stat[plane * 8 + t],
                  sms[0][0][t] + sms[1][0][t] + sms[2][0][t] + sms[3][0][t]);
    else if (t >= 64 && t < 72) {
        int k = t - 64;
        atomicAdd(&stat[64 + plane * 8 + k],
                  sms[0][1][k] + sms[1][1][k] + sms[2][1][k] + sms[3][1][k]);
    }
}

// ---- Pool: BN1(affine)+ReLU fused; reads h PLANE-MAJOR -----------------
__global__ __launch_bounds__(256) void k_pool(const bf16* h, const float* stat,
                                              const float* gam, const float* bet,
                                              const int* batch, float* pooled,
                                              float* cnt, float invN, int N) {
    int t = threadIdx.x;
    int lane = t & 63;
    float mean = stat[lane] * invN;
    float var = stat[64 + lane] * invN - mean * mean;
    float A = gam[lane] * rsqrtf(fmaxf(var, 0.f) + EPS_);
    float B = bet[lane] - mean * A;
    size_t pbase = (size_t)(lane >> 3) * N * 8 + (lane & 7);
    int w = (blockIdx.x * 256 + t) >> 6;
    int nw = (gridDim.x * 256) >> 6;
    int chunk = (N + nw - 1) / nw;
    int i0 = w * chunk;
    int i1 = i0 + chunk;
    if (i1 > N) i1 = N;
    if (i0 >= N) return;
    int curg = batch[i0];
    float acc = 0.f, c = 0.f;
    for (int i = i0; i < i1; i++) {
        int g = batch[i];
        if (g != curg) {
            atomicAdd(&pooled[(size_t)curg * 64 + lane], acc);
            if (lane == 0) atomicAdd(&cnt[curg], c);
            curg = g; acc = 0.f; c = 0.f;
        }
        acc += fmaxf(b2f(h[pbase + (size_t)i * 8]) * A + B, 0.f);
        c += 1.f;
    }
    atomicAdd(&pooled[(size_t)curg * 64 + lane], acc);
    if (lane == 0) atomicAdd(&cnt[curg], c);
}

// ---- Head --------------------------------------------------------------
__global__ __launch_bounds__(64) void k_head(const float* pooled_c, const float* cnt_c,
                                             const float* pooled_s, const float* cnt_s,
                                             const float* Wf1, const float* bf1_,
                                             const float* Wf2, const float* bf2_,
                                             float* out) {
    __shared__ float W1sm[128 * 64];
    __shared__ float W2sm[128];
    int t = threadIdx.x;  // blockDim = 64
    for (int i = t; i < 128 * 64; i += 64) W1sm[i] = Wf1[i];
    for (int i = t; i < 128; i += 64) W2sm[i] = Wf2[i];
    __syncthreads();
    float bb1 = bf1_[t];
    float b20 = bf2_[0];
    float b21 = bf2_[1];
    for (int g = blockIdx.x; g < G_; g += gridDim.x) {
        float ic = 1.f / fmaxf(cnt_c[g], 1.f);
        float is = 1.f / fmaxf(cnt_s[g], 1.f);
        float hc = pooled_c[(size_t)g * 64 + t] * ic;
        float hs = pooled_s[(size_t)g * 64 + t] * is;
        float s = bb1;
        for (int k = 0; k < 64; k++) s += __shfl(hc, k) * W1sm[k * 64 + t];
        for (int k = 0; k < 64; k++) s += __shfl(hs, k) * W1sm[(64 + k) * 64 + t];
        s = fmaxf(s, 0.f);
        float p0 = s * W2sm[t * 2 + 0];
        float p1 = s * W2sm[t * 2 + 1];
        for (int off = 32; off > 0; off >>= 1) {
            p0 += __shfl_down(p0, off);
            p1 += __shfl_down(p1, off);
        }
        if (t == 0) {
            out[g * 2 + 0] = p0 + b20;
            out[g * 2 + 1] = p1 + b21;
        }
    }
}

extern "C" void kernel_launch(void* const* d_in, const int* in_sizes, int n_in,
                              void* d_out, int out_size, void* d_ws, size_t ws_size,
                              hipStream_t stream) {
    float* out = (float*)d_out;

    if (n_in != 26 || in_sizes[0] != NC_ * 7 || in_sizes[1] != 2 * EC_ ||
        in_sizes[2] != NC_ || in_sizes[3] != NS_ * 7 || in_sizes[4] != 2 * ES_ ||
        in_sizes[5] != NS_ || out_size != G_ * 2) {
        k_fillout<<<(out_size + 255) / 256, 256, 0, stream>>>(out, 7777.0f, out_size);
        return;
    }
    if (ws_size < (size_t)WS_REQUIRED) {
        k_fillout<<<(out_size + 255) / 256, 256, 0, stream>>>(
            out, 1000.0f + (float)(ws_size >> 20), out_size);
        return;
    }

    const float* x_c     = (const float*)d_in[0];
    const int*   ei_c    = (const int*)d_in[1];
    const int*   batch_c = (const int*)d_in[2];
    const float* x_s     = (const float*)d_in[3];
    const int*   ei_s    = (const int*)d_in[4];
    const int*   batch_s = (const int*)d_in[5];
    const float* Wc0  = (const float*)d_in[6];
    const float* bc0  = (const float*)d_in[7];
    const float* gc0  = (const float*)d_in[8];
    const float* bec0 = (const float*)d_in[9];
    const float* Wc1  = (const float*)d_in[10];
    const float* bc1  = (const float*)d_in[11];
    const float* gc1  = (const float*)d_in[12];
    const float* bec1 = (const float*)d_in[13];
    const float* Ws0  = (const float*)d_in[14];
    const float* bs0  = (const float*)d_in[15];
    const float* gs0  = (const float*)d_in[16];
    const float* bes0 = (const float*)d_in[17];
    const float* Ws1  = (const float*)d_in[18];
    const float* bs1  = (const float*)d_in[19];
    const float* gs1  = (const float*)d_in[20];
    const float* bes1 = (const float*)d_in[21];
    const float* Wf1  = (const float*)d_in[22];
    const float* bf1_ = (const float*)d_in[23];
    const float* Wf2  = (const float*)d_in[24];
    const float* bf2_ = (const float*)d_in[25];

    // ---- workspace layout (4-byte words) ----
    int* wsw = (int*)d_ws;
    size_t off = 0;
    float* stats_c  = (float*)(wsw + off); off += 256;
    float* stats_s  = (float*)(wsw + off); off += 256;
    float* pooled_c = (float*)(wsw + off); off += (size_t)G_ * 64;
    float* pooled_s = (float*)(wsw + off); off += (size_t)G_ * 64;
    float* cnt_c    = (float*)(wsw + off); off += G_;
    float* cnt_s    = (float*)(wsw + off); off += G_;
    int*   bcnt_c   = wsw + off; off += NB_C;
    int*   bcnt_s   = wsw + off; off += NB_S;
    size_t zero_words = off;
    int*   bbase_c  = wsw + off; off += NB_C + 1;
    int*   bcur_c   = wsw + off; off += NB_C;
    int*   bbase_s  = wsw + off; off += NB_S + 1;
    int*   bcur_s   = wsw + off; off += NB_S;
    int*   deg      = wsw + off; off += NC_;
    int*   start    = wsw + off; off += NC_;
    int*   csr      = wsw + off; off += EC_;
    int*   ebuf     = wsw + off; off += EC_;
    off = (off + 3) & ~(size_t)3;
    bf16*  ybuf     = (bf16*)(wsw + off); off += (size_t)NC_ * 32;
    bf16*  hbuf     = (bf16*)(wsw + off); off += (size_t)NC_ * 32;
    off += 1024;   // tail pad: k_gemm1 last-tile overread
    bf16*  ubuf     = (bf16*)ybuf;   // u aliases ybuf; dead before gemm1 writes y

    k_zero<<<512, 256, 0, stream>>>(wsw, (int)zero_words);

    // ---- CSR prep ----
    k_bhist<<<256, 256, 0, stream>>>(ei_c + EC_, bcnt_c, EC_, NB_C);
    k_bhist<<<256, 256, 0, stream>>>(ei_s + ES_, bcnt_s, ES_, NB_S);
    k_bscan<<<1, 256, 0, stream>>>(bcnt_c, bbase_c, bcur_c, NB_C,
                                   bcnt_s, bbase_s, bcur_s, NB_S);

    // ---- chromo branch ----
    k_bin<<<391, 256, 0, stream>>>(ei_c, ei_c + EC_, bcur_c, ebuf, EC_, NB_C, 4096);
    k_build<<<NB_C, 256, 0, stream>>>(bbase_c, ebuf, x_c, ubuf, deg, start, csr, NC_);
    k_gather7<<<512, 256, 0, stream>>>(ubuf, csr, start, deg, Wc0, bc0, hbuf, stats_c, NC_);
    k_gemm1<<<512, 256, 0, stream>>>(hbuf, Wc1, stats_c, gc0, bec0, deg, ybuf, 1.0f / NC_, NC_);
    k_gather8<<<2048, 256, 0, stream>>>(ybuf, csr, start, deg, bc1, hbuf, stats_c + 128, NC_);
    k_pool<<<256, 256, 0, stream>>>(hbuf, stats_c + 128, gc1, bec1, batch_c, pooled_c, cnt_c, 1.0f / NC_, NC_);

    // ---- solvent branch ----
    k_bin<<<391, 256, 0, stream>>>(ei_s, ei_s + ES_, bcur_s, ebuf, ES_, NB_S, 2048);
    k_build<<<NB_S, 256, 0, stream>>>(bbase_s, ebuf, x_s, ubuf, deg, start, csr, NS_);
    k_gather7<<<256, 256, 0, stream>>>(ubuf, csr, start, deg, Ws0, bs0, hbuf, stats_s, NS_);
    k_gemm1<<<512, 256, 0, stream>>>(hbuf, Ws1, stats_s, gs0, bes0, deg, ybuf, 1.0f / NS_, NS_);
    k_gather8<<<1024, 256, 0, stream>>>(ybuf, csr, start, deg, bs1, hbuf, stats_s + 128, NS_);
    k_pool<<<256, 256, 0, stream>>>(hbuf, stats_s + 128, gs1, bes1, batch_s, pooled_s, cnt_s, 1.0f / NS_, NS_);

    // ---- head ----
    k_head<<<128, 64, 0, stream>>>(pooled_c, cnt_c, pooled_s, cnt_s, Wf1, bf1_, Wf2, bf2_, out);
}

// Round 13
// 469.759 us; speedup vs baseline: 1.5992x; 1.0160x over previous
//
#include <hip/hip_runtime.h>
#include <hip/hip_bf16.h>

typedef __hip_bfloat16 bf16;
typedef __attribute__((ext_vector_type(8))) short short8;
typedef __attribute__((ext_vector_type(4))) float f32x4;

#define NC_ 100000
#define EC_ 1600000
#define NS_ 50000
#define ES_ 800000
#define G_  1024
#define EPS_ 1e-5f

#define NB_C 782          // ceil(100000/128)
#define NB_S 391          // ceil(50000/128)
#define NBMAX 782
#define KSL 16            // LDS slots per bucket in k_bin
#define CSR_WORDS 2000400 // EC_ + 512*NB_C + 16 (aligned-CSR slack)

#define WS_REQUIRED 34961500ull

__device__ __forceinline__ float b2f(bf16 v) { return __bfloat162float(v); }

__device__ __forceinline__ unsigned short f2bfbits(float v) {
    bf16 b = __float2bfloat16(v);
    union { bf16 b; unsigned short u; } c; c.b = b; return c.u;
}

__device__ __forceinline__ void acc8(float* a, uint4 r) {
    a[0] += __uint_as_float(r.x << 16); a[1] += __uint_as_float(r.x & 0xffff0000u);
    a[2] += __uint_as_float(r.y << 16); a[3] += __uint_as_float(r.y & 0xffff0000u);
    a[4] += __uint_as_float(r.z << 16); a[5] += __uint_as_float(r.z & 0xffff0000u);
    a[6] += __uint_as_float(r.w << 16); a[7] += __uint_as_float(r.w & 0xffff0000u);
}

__global__ void DualGNN_31327491457689_kernel() {}

__global__ __launch_bounds__(256) void k_fillout(float* out, float val, int n) {
    int i = blockIdx.x * 256 + threadIdx.x;
    if (i < n) out[i] = val;
}

__global__ __launch_bounds__(256) void k_zero(int* p, int n) {
    int i = blockIdx.x * 256 + threadIdx.x;
    int stride = gridDim.x * 256;
    while (i < n) { p[i] = 0; i += stride; }
}

// ---- Phase A: bucket histogram (LDS-staged) ----------------------------
__global__ __launch_bounds__(256) void k_bhist(const int* dst, int* bcnt, int E, int NB) {
    __shared__ int h[NBMAX];
    int t = threadIdx.x;
    for (int i = t; i < NB; i += 256) h[i] = 0;
    __syncthreads();
    for (int e = blockIdx.x * 256 + t; e < E; e += gridDim.x * 256)
        atomicAdd(&h[dst[e] >> 7], 1);
    __syncthreads();
    for (int i = t; i < NB; i += 256) {
        int v = h[i];
        if (v) atomicAdd(&bcnt[i], v);
    }
}

// ---- Phase B: scan bucket counts (both branches, one block) ------------
__device__ void scan_one(const int* cnt, int* base, int* cur, int NB, int (*sc)[1024]) {
    int t = threadIdx.x;
    for (int i = t; i < 1024; i += 256) sc[0][i] = (i < NB) ? cnt[i] : 0;
    __syncthreads();
    int pin = 0;
    for (int off = 1; off < 1024; off <<= 1) {
        for (int i = t; i < 1024; i += 256) {
            int v = sc[pin][i];
            if (i >= off) v += sc[pin][i - off];
            sc[1 - pin][i] = v;
        }
        __syncthreads();
        pin ^= 1;
    }
    for (int i = t; i <= NB; i += 256) {
        int e = (i == 0) ? 0 : sc[pin][i - 1];
        base[i] = e;
        if (i < NB) cur[i] = e;
    }
    __syncthreads();
}

__global__ __launch_bounds__(256) void k_bscan(const int* cnt_c, int* base_c, int* cur_c, int NBc,
                                               const int* cnt_s, int* base_s, int* cur_s, int NBs) {
    __shared__ int sc[2][1024];
    scan_one(cnt_c, base_c, cur_c, NBc, sc);
    scan_one(cnt_s, base_s, cur_s, NBs, sc);
}

// ---- Phase C: bin packed edges into bucket-partitioned streams ---------
__global__ __launch_bounds__(256) void k_bin(const int* src, const int* dst, int* bcur,
                                             int* ebuf, int E, int NB, int CHUNK) {
    __shared__ int cnt[NBMAX];
    __shared__ int slot[NBMAX * KSL];
    int t = threadIdx.x;
    for (long long base = (long long)blockIdx.x * CHUNK; base < E;
         base += (long long)gridDim.x * CHUNK) {
        for (int i = t; i < NB; i += 256) cnt[i] = 0;
        __syncthreads();
        int e1 = (int)base + CHUNK;
        if (e1 > E) e1 = E;
        for (int e = (int)base + t; e < e1; e += 256) {
            int d = dst[e];
            int p = ((d & 127) << 24) | src[e];
            int b = d >> 7;
            int sl = atomicAdd(&cnt[b], 1);
            if (sl < KSL) slot[b * KSL + sl] = p;
            else { int gp = atomicAdd(&bcur[b], 1); ebuf[gp] = p; }
        }
        __syncthreads();
        for (int b = t; b < NB; b += 256) {
            int c = cnt[b];
            if (c > KSL) c = KSL;
            if (c > 0) {
                int gp = atomicAdd(&bcur[b], c);
                for (int k = 0; k < c; k++) ebuf[gp + k] = slot[b * KSL + k];
            }
        }
        __syncthreads();
    }
}

// ---- Phase D: per-bucket build, 4-ALIGNED csr + sentinel pads + u prep --
// csr window per bucket at cb = align4(bbase[b] + 512*b); per-node lists
// padded to x4 with sentinel N (row N of u/y is zeroed).
__global__ __launch_bounds__(256) void k_build(const int* bbase, const int* ebuf,
                                               const float* x, bf16* u,
                                               int* deg, int* start, int* csr, int N) {
    __shared__ int lcnt[128], lofs[128], lcur[128];
    int b = blockIdx.x, t = threadIdx.x;
    int e0 = bbase[b], e1 = bbase[b + 1];
    int cb = ((e0 + 512 * b) + 3) & ~3;
    int n0 = b << 7;
    if (t < 128) lcnt[t] = 0;
    __syncthreads();
    for (int e = e0 + t; e < e1; e += 256)
        atomicAdd(&lcnt[((unsigned)ebuf[e]) >> 24], 1);
    __syncthreads();
    if (t < 64) {   // exclusive scan of ALIGNED counts, 2 per lane
        int c0 = lcnt[2 * t], c1 = lcnt[2 * t + 1];
        int v0 = (c0 + 3) & ~3, v1 = (c1 + 3) & ~3;
        int s = v0 + v1, incl = s;
        for (int off = 1; off < 64; off <<= 1) {
            int uu = __shfl_up(incl, off);
            if (t >= off) incl += uu;
        }
        int excl = incl - s;
        lofs[2 * t] = excl;
        lofs[2 * t + 1] = excl + v0;
    }
    __syncthreads();
    if (t < 128) {
        int node = n0 + t;
        if (node < N) {
            deg[node] = lcnt[t];
            start[node] = cb + lofs[t];
            float d = rsqrtf((float)(lcnt[t] + 1));
            union __align__(16) Pack { bf16 hh[8]; uint4 v; } p;
            for (int k = 0; k < 7; k++) p.hh[k] = __float2bfloat16(x[node * 7 + k] * d);
            p.hh[7] = __float2bfloat16(0.f);
            ((uint4*)u)[node] = p.v;
        }
        lcur[t] = lofs[t];
    }
    __syncthreads();
    if (t < 128) {   // sentinel pads (disjoint from scatter range)
        int c = lcnt[t], al = (c + 3) & ~3;
        for (int k = c; k < al; k++) csr[cb + lofs[t] + k] = N;
    }
    for (int e = e0 + t; e < e1; e += 256) {
        unsigned p = (unsigned)ebuf[e];
        int dl = p >> 24;
        int pos = atomicAdd(&lcur[dl], 1);
        csr[cb + pos] = (int)(p & 0xFFFFFF);
    }
    if (b == 0 && t < 4) ((int*)u)[N * 4 + t] = 0;   // zero sentinel row of u
}

// ---- Layer 0 gather in rank-7 space + fused 7x64 GEMM + bias + stats ---
__global__ __launch_bounds__(256) void k_gather7(const bf16* u, const int* csr,
                                                 const int* start, const int* deg,
                                                 const float* W, const float* bias,
                                                 bf16* h, float* stat, int N) {
    __shared__ float Wsm[7 * 64];
    __shared__ float agg[256][9];
    __shared__ float sm[2][4][64];
    int t = threadIdx.x, lane = t & 63, ty = t >> 6;
    for (int i = t; i < 448; i += 256) Wsm[i] = W[i];
    float b = bias[lane];
    float sum = 0.f, sq = 0.f;
    const uint4* up = (const uint4*)u;
    for (int base = blockIdx.x * 256; base < N; base += gridDim.x * 256) {
        __syncthreads();
        int i = base + t;
        float a[8] = {0.f, 0.f, 0.f, 0.f, 0.f, 0.f, 0.f, 0.f};
        if (i < N) {
            int dg = deg[i], s0 = start[i];
            int adeg = (dg + 3) & ~3;
            acc8(a, up[i]);
            for (int j = 0; j < adeg; j += 4) {
                uint4 nb = *(const uint4*)(csr + s0 + j);   // 16B-aligned
                uint4 r0 = up[nb.x], r1 = up[nb.y], r2 = up[nb.z], r3 = up[nb.w];
                acc8(a, r0); acc8(a, r1); acc8(a, r2); acc8(a, r3);
            }
            float di = rsqrtf((float)(dg + 1));
            for (int k = 0; k < 7; k++) a[k] *= di;
        }
        #pragma unroll
        for (int k = 0; k < 7; k++) agg[t][k] = a[k];
        __syncthreads();
        int mbase = base + ty * 64;
        for (int mm = 0; mm < 64; mm++) {
            int node = mbase + mm;
            if (node >= N) break;
            const float* ag = agg[ty * 64 + mm];
            float s = b;
            #pragma unroll
            for (int k = 0; k < 7; k++) s += ag[k] * Wsm[k * 64 + lane];
            h[(size_t)node * 64 + lane] = __float2bfloat16(s);
            sum += s; sq += s * s;
        }
    }
    sm[0][ty][lane] = sum;
    sm[1][ty][lane] = sq;
    __syncthreads();
    if (ty == 0) {
        atomicAdd(&stat[lane],      sm[0][0][lane] + sm[0][1][lane] + sm[0][2][lane] + sm[0][3][lane]);
        atomicAdd(&stat[64 + lane], sm[1][0][lane] + sm[1][1][lane] + sm[1][2][lane] + sm[1][3][lane]);
    }
}

// ---- Layer 1 GEMM via MFMA; writes y PAIR-MAJOR: [(c>>4)*NY+node]*16+(c&15)
__global__ __launch_bounds__(256) void k_gemm1(const bf16* h, const float* W,
                                               const float* stat, const float* gam,
                                               const float* bet, const int* deg,
                                               bf16* y, float invN, int N, int NY) {
    __shared__ short Wt[64][72];
    __shared__ float AB[128];
    int t = threadIdx.x, lane = t & 63, ty = t >> 6;
    for (int i = t; i < 4096; i += 256) {
        int k = i >> 6, n = i & 63;
        Wt[n][k] = (short)f2bfbits(W[i]);
    }
    if (t < 64) {
        float mean = stat[t] * invN;
        float var = stat[64 + t] * invN - mean * mean;
        float A = gam[t] * rsqrtf(fmaxf(var, 0.f) + EPS_);
        AB[t] = A;
        AB[64 + t] = bet[t] - mean * A;
    }
    if (blockIdx.x == 0 && t < 64) {     // zero sentinel row N of each pair
        int pr = t >> 4, cl = t & 15;
        y[((size_t)pr * NY + N) * 16 + cl] = __float2bfloat16(0.f);
    }
    __syncthreads();
    int quad = lane >> 4, l16 = lane & 15;
    short8 Bf[2][4];
    #pragma unroll
    for (int kt = 0; kt < 2; kt++)
        #pragma unroll
        for (int nt = 0; nt < 4; nt++) {
            int n = nt * 16 + l16, k0 = kt * 32 + quad * 8;
            Bf[kt][nt] = *(const short8*)&Wt[n][k0];
        }
    int ntile = (N + 63) >> 6;
    for (int tile = blockIdx.x * 4 + ty; tile < ntile; tile += gridDim.x * 4) {
        int base = tile << 6;
        f32x4 acc[4][4];
        #pragma unroll
        for (int a = 0; a < 4; a++)
            #pragma unroll
            for (int b = 0; b < 4; b++) acc[a][b] = (f32x4){0.f, 0.f, 0.f, 0.f};
        #pragma unroll
        for (int kt = 0; kt < 2; kt++) {
            int k0 = kt * 32 + quad * 8;
            float Ak[8], Bk[8];
            #pragma unroll
            for (int j = 0; j < 8; j++) { Ak[j] = AB[k0 + j]; Bk[j] = AB[64 + k0 + j]; }
            #pragma unroll
            for (int mt = 0; mt < 4; mt++) {
                int node = base + mt * 16 + l16;     // tail overread: hbuf padded
                uint4 raw = *(const uint4*)(h + (size_t)node * 64 + k0);
                unsigned rr[4] = {raw.x, raw.y, raw.z, raw.w};
                short8 af;
                #pragma unroll
                for (int j = 0; j < 8; j++) {
                    unsigned bits = (j & 1) ? (rr[j >> 1] & 0xffff0000u)
                                            : (rr[j >> 1] << 16);
                    float v = __uint_as_float(bits);
                    v = fmaxf(v * Ak[j] + Bk[j], 0.f);
                    af[j] = (short)f2bfbits(v);
                }
                #pragma unroll
                for (int nt = 0; nt < 4; nt++)
                    acc[mt][nt] = __builtin_amdgcn_mfma_f32_16x16x32_bf16(
                        af, Bf[kt][nt], acc[mt][nt], 0, 0, 0);
            }
        }
        #pragma unroll
        for (int mt = 0; mt < 4; mt++)
            #pragma unroll
            for (int r = 0; r < 4; r++) {
                int node = base + mt * 16 + quad * 4 + r;
                if (node < N) {
                    float dinv = rsqrtf((float)(deg[node] + 1));
                    #pragma unroll
                    for (int nt = 0; nt < 4; nt++)
                        y[((size_t)nt * NY + node) * 16 + l16] =
                            __float2bfloat16(acc[mt][nt][r] * dinv);
                }
            }
    }
}

// ---- Layer-1 gather: 16-ch pairs, XCD-pinned via blockIdx&3 ------------
// y/h: [pair][NY][16ch] bf16 (32 B rows; 3.2 MB/pair -> L2-resident)
__global__ __launch_bounds__(256) void k_gather16(const bf16* y, const int* csr,
                                                  const int* start, const int* deg,
                                                  const float* bias, bf16* h,
                                                  float* stat, int N, int NY) {
    __shared__ float sms[4][2][16];
    int t = threadIdx.x, lane = t & 63, ty = t >> 6;
    int pair = blockIdx.x & 3;
    int grp = blockIdx.x >> 2;
    int ngrp = gridDim.x >> 2;
    const uint4* yp = (const uint4*)y + (size_t)pair * NY * 2;
    uint4* hp = (uint4*)h + (size_t)pair * NY * 2;
    float b[16];
    #pragma unroll
    for (int k = 0; k < 16; k++) b[k] = bias[pair * 16 + k];
    float sum[16], sq[16];
    #pragma unroll
    for (int k = 0; k < 16; k++) { sum[k] = 0.f; sq[k] = 0.f; }
    for (int i = grp * 256 + t; i < N; i += ngrp * 256) {
        int dg = deg[i], s0 = start[i];
        int adeg = (dg + 3) & ~3;
        float a[16];
        #pragma unroll
        for (int k = 0; k < 16; k++) a[k] = 0.f;
        { uint4 r0 = yp[2 * i], r1 = yp[2 * i + 1]; acc8(a, r0); acc8(a + 8, r1); }
        for (int j = 0; j < adeg; j += 4) {
            uint4 nb = *(const uint4*)(csr + s0 + j);   // 1 req / 4 edges
            uint4 q0 = yp[2 * nb.x], q1 = yp[2 * nb.x + 1];   // adjacent pair:
            uint4 q2 = yp[2 * nb.y], q3 = yp[2 * nb.y + 1];   // same 64B line
            uint4 q4 = yp[2 * nb.z], q5 = yp[2 * nb.z + 1];
            uint4 q6 = yp[2 * nb.w], q7 = yp[2 * nb.w + 1];
            acc8(a, q0); acc8(a + 8, q1);
            acc8(a, q2); acc8(a + 8, q3);
            acc8(a, q4); acc8(a + 8, q5);
            acc8(a, q6); acc8(a + 8, q7);
        }
        float di = rsqrtf((float)(dg + 1));
        union __align__(16) Pack { bf16 hh[16]; uint4 v[2]; } p;
        #pragma unroll
        for (int k = 0; k < 16; k++) {
            float v = a[k] * di + b[k];
            p.hh[k] = __float2bfloat16(v);
            sum[k] += v; sq[k] += v * v;
        }
        hp[2 * i] = p.v[0];
        hp[2 * i + 1] = p.v[1];
    }
    #pragma unroll
    for (int k = 0; k < 16; k++) {
        float s1 = sum[k], s2 = sq[k];
        for (int off = 32; off > 0; off >>= 1) {
            s1 += __shfl_down(s1, off);
            s2 += __shfl_down(s2, off);
        }
        if (lane == 0) { sms[ty][0][k] = s1; sms[ty][1][k] = s2; }
    }
    __syncthreads();
    if (t < 16)
        atomicAdd(&stat[pair * 16 + t],
                  sms[0][0][t] + sms[1][0][t] + sms[2][0][t] + sms[3][0][t]);
    else if (t >= 64 && t < 80) {
        int k = t - 64;
        atomicAdd(&stat[64 + pair * 16 + k],
                  sms[0][1][k] + sms[1][1][k] + sms[2][1][k] + sms[3][1][k]);
    }
}

// ---- Pool: BN1(affine)+ReLU fused; reads h PAIR-MAJOR ------------------
__global__ __launch_bounds__(256) void k_pool(const bf16* h, const float* stat,
                                              const float* gam, const float* bet,
                                              const int* batch, float* pooled,
                                              float* cnt, float invN, int N, int NY) {
    int t = threadIdx.x;
    int lane = t & 63;
    float mean = stat[lane] * invN;
    float var = stat[64 + lane] * invN - mean * mean;
    float A = gam[lane] * rsqrtf(fmaxf(var, 0.f) + EPS_);
    float B = bet[lane] - mean * A;
    size_t pbase = (size_t)(lane >> 4) * NY * 16 + (lane & 15);
    int w = (blockIdx.x * 256 + t) >> 6;
    int nw = (gridDim.x * 256) >> 6;
    int chunk = (N + nw - 1) / nw;
    int i0 = w * chunk;
    int i1 = i0 + chunk;
    if (i1 > N) i1 = N;
    if (i0 >= N) return;
    int curg = batch[i0];
    float acc = 0.f, c = 0.f;
    for (int i = i0; i < i1; i++) {
        int g = batch[i];
        if (g != curg) {
            atomicAdd(&pooled[(size_t)curg * 64 + lane], acc);
            if (lane == 0) atomicAdd(&cnt[curg], c);
            curg = g; acc = 0.f; c = 0.f;
        }
        acc += fmaxf(b2f(h[pbase + (size_t)i * 16]) * A + B, 0.f);
        c += 1.f;
    }
    atomicAdd(&pooled[(size_t)curg * 64 + lane], acc);
    if (lane == 0) atomicAdd(&cnt[curg], c);
}

// ---- Head --------------------------------------------------------------
__global__ __launch_bounds__(64) void k_head(const float* pooled_c, const float* cnt_c,
                                             const float* pooled_s, const float* cnt_s,
                                             const float* Wf1, const float* bf1_,
                                             const float* Wf2, const float* bf2_,
                                             float* out) {
    __shared__ float W1sm[128 * 64];
    __shared__ float W2sm[128];
    int t = threadIdx.x;  // blockDim = 64
    for (int i = t; i < 128 * 64; i += 64) W1sm[i] = Wf1[i];
    for (int i = t; i < 128; i += 64) W2sm[i] = Wf2[i];
    __syncthreads();
    float bb1 = bf1_[t];
    float b20 = bf2_[0];
    float b21 = bf2_[1];
    for (int g = blockIdx.x; g < G_; g += gridDim.x) {
        float ic = 1.f / fmaxf(cnt_c[g], 1.f);
        float is = 1.f / fmaxf(cnt_s[g], 1.f);
        float hc = pooled_c[(size_t)g * 64 + t] * ic;
        float hs = pooled_s[(size_t)g * 64 + t] * is;
        float s = bb1;
        for (int k = 0; k < 64; k++) s += __shfl(hc, k) * W1sm[k * 64 + t];
        for (int k = 0; k < 64; k++) s += __shfl(hs, k) * W1sm[(64 + k) * 64 + t];
        s = fmaxf(s, 0.f);
        float p0 = s * W2sm[t * 2 + 0];
        float p1 = s * W2sm[t * 2 + 1];
        for (int off = 32; off > 0; off >>= 1) {
            p0 += __shfl_down(p0, off);
            p1 += __shfl_down(p1, off);
        }
        if (t == 0) {
            out[g * 2 + 0] = p0 + b20;
            out[g * 2 + 1] = p1 + b21;
        }
    }
}

extern "C" void kernel_launch(void* const* d_in, const int* in_sizes, int n_in,
                              void* d_out, int out_size, void* d_ws, size_t ws_size,
                              hipStream_t stream) {
    float* out = (float*)d_out;

    if (n_in != 26 || in_sizes[0] != NC_ * 7 || in_sizes[1] != 2 * EC_ ||
        in_sizes[2] != NC_ || in_sizes[3] != NS_ * 7 || in_sizes[4] != 2 * ES_ ||
        in_sizes[5] != NS_ || out_size != G_ * 2) {
        k_fillout<<<(out_size + 255) / 256, 256, 0, stream>>>(out, 7777.0f, out_size);
        return;
    }
    if (ws_size < (size_t)WS_REQUIRED) {
        k_fillout<<<(out_size + 255) / 256, 256, 0, stream>>>(
            out, 1000.0f + (float)(ws_size >> 20), out_size);
        return;
    }

    const float* x_c     = (const float*)d_in[0];
    const int*   ei_c    = (const int*)d_in[1];
    const int*   batch_c = (const int*)d_in[2];
    const float* x_s     = (const float*)d_in[3];
    const int*   ei_s    = (const int*)d_in[4];
    const int*   batch_s = (const int*)d_in[5];
    const float* Wc0  = (const float*)d_in[6];
    const float* bc0  = (const float*)d_in[7];
    const float* gc0  = (const float*)d_in[8];
    const float* bec0 = (const float*)d_in[9];
    const float* Wc1  = (const float*)d_in[10];
    const float* bc1  = (const float*)d_in[11];
    const float* gc1  = (const float*)d_in[12];
    const float* bec1 = (const float*)d_in[13];
    const float* Ws0  = (const float*)d_in[14];
    const float* bs0  = (const float*)d_in[15];
    const float* gs0  = (const float*)d_in[16];
    const float* bes0 = (const float*)d_in[17];
    const float* Ws1  = (const float*)d_in[18];
    const float* bs1  = (const float*)d_in[19];
    const float* gs1  = (const float*)d_in[20];
    const float* bes1 = (const float*)d_in[21];
    const float* Wf1  = (const float*)d_in[22];
    const float* bf1_ = (const float*)d_in[23];
    const float* Wf2  = (const float*)d_in[24];
    const float* bf2_ = (const float*)d_in[25];

    const int NYC = NC_ + 8;   // pair-plane stride (chromo), row NC_ = zero sentinel
    const int NYS = NS_ + 8;

    // ---- workspace layout (4-byte words); ~35.0 MB ----
    int* wsw = (int*)d_ws;
    size_t off = 0;
    float* stats_c  = (float*)(wsw + off); off += 256;
    float* stats_s  = (float*)(wsw + off); off += 256;
    float* pooled_c = (float*)(wsw + off); off += (size_t)G_ * 64;
    float* pooled_s = (float*)(wsw + off); off += (size_t)G_ * 64;
    float* cnt_c    = (float*)(wsw + off); off += G_;
    float* cnt_s    = (float*)(wsw + off); off += G_;
    int*   bcnt_c   = wsw + off; off += NB_C;
    int*   bcnt_s   = wsw + off; off += NB_S;
    size_t zero_words = off;
    int*   bbase_c  = wsw + off; off += NB_C + 1;
    int*   bcur_c   = wsw + off; off += NB_C;
    int*   bbase_s  = wsw + off; off += NB_S + 1;
    int*   bcur_s   = wsw + off; off += NB_S;
    int*   deg      = wsw + off; off += NC_;
    int*   start    = wsw + off; off += NC_;
    int*   csr      = wsw + off; off += CSR_WORDS;
    off = (off + 3) & ~(size_t)3;
    bf16*  hbuf     = (bf16*)(wsw + off); off += 3202560;   // row-major N+64 rows / pair-planes
    bf16*  ybuf     = (bf16*)(wsw + off); off += 3200256;   // 4 * NYC * 16 halfwords
    int*   ebuf     = (int*)hbuf;   // ebuf aliases hbuf (dead before gather7 writes h)
    bf16*  ubuf     = ybuf;         // u aliases ybuf (dead before gemm1 writes y)

    k_zero<<<512, 256, 0, stream>>>(wsw, (int)zero_words);

    // ---- CSR prep ----
    k_bhist<<<256, 256, 0, stream>>>(ei_c + EC_, bcnt_c, EC_, NB_C);
    k_bhist<<<256, 256, 0, stream>>>(ei_s + ES_, bcnt_s, ES_, NB_S);
    k_bscan<<<1, 256, 0, stream>>>(bcnt_c, bbase_c, bcur_c, NB_C,
                                   bcnt_s, bbase_s, bcur_s, NB_S);

    // ---- chromo branch ----
    k_bin<<<391, 256, 0, stream>>>(ei_c, ei_c + EC_, bcur_c, ebuf, EC_, NB_C, 4096);
    k_build<<<NB_C, 256, 0, stream>>>(bbase_c, ebuf, x_c, ubuf, deg, start, csr, NC_);
    k_gather7<<<512, 256, 0, stream>>>(ubuf, csr, start, deg, Wc0, bc0, hbuf, stats_c, NC_);
    k_gemm1<<<512, 256, 0, stream>>>(hbuf, Wc1, stats_c, gc0, bec0, deg, ybuf, 1.0f / NC_, NC_, NYC);
    k_gather16<<<2048, 256, 0, stream>>>(ybuf, csr, start, deg, bc1, hbuf, stats_c + 128, NC_, NYC);
    k_pool<<<256, 256, 0, stream>>>(hbuf, stats_c + 128, gc1, bec1, batch_c, pooled_c, cnt_c, 1.0f / NC_, NC_, NYC);

    // ---- solvent branch ----
    k_bin<<<391, 256, 0, stream>>>(ei_s, ei_s + ES_, bcur_s, ebuf, ES_, NB_S, 2048);
    k_build<<<NB_S, 256, 0, stream>>>(bbase_s, ebuf, x_s, ubuf, deg, start, csr, NS_);
    k_gather7<<<256, 256, 0, stream>>>(ubuf, csr, start, deg, Ws0, bs0, hbuf, stats_s, NS_);
    k_gemm1<<<512, 256, 0, stream>>>(hbuf, Ws1, stats_s, gs0, bes0, deg, ybuf, 1.0f / NS_, NS_, NYS);
    k_gather16<<<1024, 256, 0, stream>>>(ybuf, csr, start, deg, bs1, hbuf, stats_s + 128, NS_, NYS);
    k_pool<<<256, 256, 0, stream>>>(hbuf, stats_s + 128, gs1, bes1, batch_s, pooled_s, cnt_s, 1.0f / NS_, NS_, NYS);

    // ---- head ----
    k_head<<<128, 64, 0, stream>>>(pooled_c, cnt_c, pooled_s, cnt_s, Wf1, bf1_, Wf2, bf2_, out);
}

// Round 14
// 457.344 us; speedup vs baseline: 1.6427x; 1.0271x over previous
//
#include <hip/hip_runtime.h>
#include <hip/hip_bf16.h>

typedef __hip_bfloat16 bf16;
typedef __attribute__((ext_vector_type(8))) short short8;
typedef __attribute__((ext_vector_type(4))) float f32x4;

#define NC_ 100000
#define EC_ 1600000
#define NS_ 50000
#define ES_ 800000
#define G_  1024
#define EPS_ 1e-5f

#define NB_C 782          // ceil(100000/128)
#define NB_S 391          // ceil(50000/128)
#define NBMAX 782
#define KSL 16            // LDS slots per bucket in k_bin
#define CSR_WORDS 2000400 // EC_ + 512*NB_C + 16 (aligned-CSR slack)

#define WS_REQUIRED 34961500ull

__device__ __forceinline__ float b2f(bf16 v) { return __bfloat162float(v); }

__device__ __forceinline__ unsigned short f2bfbits(float v) {
    bf16 b = __float2bfloat16(v);
    union { bf16 b; unsigned short u; } c; c.b = b; return c.u;
}

__device__ __forceinline__ void acc8(float* a, uint4 r) {
    a[0] += __uint_as_float(r.x << 16); a[1] += __uint_as_float(r.x & 0xffff0000u);
    a[2] += __uint_as_float(r.y << 16); a[3] += __uint_as_float(r.y & 0xffff0000u);
    a[4] += __uint_as_float(r.z << 16); a[5] += __uint_as_float(r.z & 0xffff0000u);
    a[6] += __uint_as_float(r.w << 16); a[7] += __uint_as_float(r.w & 0xffff0000u);
}

__global__ void DualGNN_31327491457689_kernel() {}

__global__ __launch_bounds__(256) void k_fillout(float* out, float val, int n) {
    int i = blockIdx.x * 256 + threadIdx.x;
    if (i < n) out[i] = val;
}

__global__ __launch_bounds__(256) void k_zero(int* p, int n) {
    int i = blockIdx.x * 256 + threadIdx.x;
    int stride = gridDim.x * 256;
    while (i < n) { p[i] = 0; i += stride; }
}

// ---- Phase A: bucket histogram (LDS-staged) ----------------------------
__global__ __launch_bounds__(256) void k_bhist(const int* dst, int* bcnt, int E, int NB) {
    __shared__ int h[NBMAX];
    int t = threadIdx.x;
    for (int i = t; i < NB; i += 256) h[i] = 0;
    __syncthreads();
    for (int e = blockIdx.x * 256 + t; e < E; e += gridDim.x * 256)
        atomicAdd(&h[dst[e] >> 7], 1);
    __syncthreads();
    for (int i = t; i < NB; i += 256) {
        int v = h[i];
        if (v) atomicAdd(&bcnt[i], v);
    }
}

// ---- Phase B: scan bucket counts (both branches, one block) ------------
__device__ void scan_one(const int* cnt, int* base, int* cur, int NB, int (*sc)[1024]) {
    int t = threadIdx.x;
    for (int i = t; i < 1024; i += 256) sc[0][i] = (i < NB) ? cnt[i] : 0;
    __syncthreads();
    int pin = 0;
    for (int off = 1; off < 1024; off <<= 1) {
        for (int i = t; i < 1024; i += 256) {
            int v = sc[pin][i];
            if (i >= off) v += sc[pin][i - off];
            sc[1 - pin][i] = v;
        }
        __syncthreads();
        pin ^= 1;
    }
    for (int i = t; i <= NB; i += 256) {
        int e = (i == 0) ? 0 : sc[pin][i - 1];
        base[i] = e;
        if (i < NB) cur[i] = e;
    }
    __syncthreads();
}

__global__ __launch_bounds__(256) void k_bscan(const int* cnt_c, int* base_c, int* cur_c, int NBc,
                                               const int* cnt_s, int* base_s, int* cur_s, int NBs) {
    __shared__ int sc[2][1024];
    scan_one(cnt_c, base_c, cur_c, NBc, sc);
    scan_one(cnt_s, base_s, cur_s, NBs, sc);
}

// ---- Phase C: bin packed edges into bucket-partitioned streams ---------
__global__ __launch_bounds__(256) void k_bin(const int* src, const int* dst, int* bcur,
                                             int* ebuf, int E, int NB, int CHUNK) {
    __shared__ int cnt[NBMAX];
    __shared__ int slot[NBMAX * KSL];
    int t = threadIdx.x;
    for (long long base = (long long)blockIdx.x * CHUNK; base < E;
         base += (long long)gridDim.x * CHUNK) {
        for (int i = t; i < NB; i += 256) cnt[i] = 0;
        __syncthreads();
        int e1 = (int)base + CHUNK;
        if (e1 > E) e1 = E;
        for (int e = (int)base + t; e < e1; e += 256) {
            int d = dst[e];
            int p = ((d & 127) << 24) | src[e];
            int b = d >> 7;
            int sl = atomicAdd(&cnt[b], 1);
            if (sl < KSL) slot[b * KSL + sl] = p;
            else { int gp = atomicAdd(&bcur[b], 1); ebuf[gp] = p; }
        }
        __syncthreads();
        for (int b = t; b < NB; b += 256) {
            int c = cnt[b];
            if (c > KSL) c = KSL;
            if (c > 0) {
                int gp = atomicAdd(&bcur[b], c);
                for (int k = 0; k < c; k++) ebuf[gp + k] = slot[b * KSL + k];
            }
        }
        __syncthreads();
    }
}

// ---- Phase D: per-bucket build, 4-ALIGNED csr + sentinel pads + u prep --
__global__ __launch_bounds__(256) void k_build(const int* bbase, const int* ebuf,
                                               const float* x, bf16* u,
                                               int* deg, int* start, int* csr, int N) {
    __shared__ int lcnt[128], lofs[128], lcur[128];
    int b = blockIdx.x, t = threadIdx.x;
    int e0 = bbase[b], e1 = bbase[b + 1];
    int cb = ((e0 + 512 * b) + 3) & ~3;
    int n0 = b << 7;
    if (t < 128) lcnt[t] = 0;
    __syncthreads();
    for (int e = e0 + t; e < e1; e += 256)
        atomicAdd(&lcnt[((unsigned)ebuf[e]) >> 24], 1);
    __syncthreads();
    if (t < 64) {   // exclusive scan of ALIGNED counts, 2 per lane
        int c0 = lcnt[2 * t], c1 = lcnt[2 * t + 1];
        int v0 = (c0 + 3) & ~3, v1 = (c1 + 3) & ~3;
        int s = v0 + v1, incl = s;
        for (int off = 1; off < 64; off <<= 1) {
            int uu = __shfl_up(incl, off);
            if (t >= off) incl += uu;
        }
        int excl = incl - s;
        lofs[2 * t] = excl;
        lofs[2 * t + 1] = excl + v0;
    }
    __syncthreads();
    if (t < 128) {
        int node = n0 + t;
        if (node < N) {
            deg[node] = lcnt[t];
            start[node] = cb + lofs[t];
            float d = rsqrtf((float)(lcnt[t] + 1));
            union __align__(16) Pack { bf16 hh[8]; uint4 v; } p;
            for (int k = 0; k < 7; k++) p.hh[k] = __float2bfloat16(x[node * 7 + k] * d);
            p.hh[7] = __float2bfloat16(0.f);
            ((uint4*)u)[node] = p.v;
        }
        lcur[t] = lofs[t];
    }
    __syncthreads();
    if (t < 128) {   // sentinel pads (disjoint from scatter range)
        int c = lcnt[t], al = (c + 3) & ~3;
        for (int k = c; k < al; k++) csr[cb + lofs[t] + k] = N;
    }
    for (int e = e0 + t; e < e1; e += 256) {
        unsigned p = (unsigned)ebuf[e];
        int dl = p >> 24;
        int pos = atomicAdd(&lcur[dl], 1);
        csr[cb + pos] = (int)(p & 0xFFFFFF);
    }
    if (b == 0 && t < 4) ((int*)u)[N * 4 + t] = 0;   // zero sentinel row of u
}

// ---- Layer 0 gather in rank-7 space + fused 7x64 GEMM + bias + stats ---
__global__ __launch_bounds__(256) void k_gather7(const bf16* u, const int* csr,
                                                 const int* start, const int* deg,
                                                 const float* W, const float* bias,
                                                 bf16* h, float* stat, int N) {
    __shared__ float Wsm[7 * 64];
    __shared__ float agg[256][9];
    __shared__ float sm[2][4][64];
    int t = threadIdx.x, lane = t & 63, ty = t >> 6;
    for (int i = t; i < 448; i += 256) Wsm[i] = W[i];
    float b = bias[lane];
    float sum = 0.f, sq = 0.f;
    const uint4* up = (const uint4*)u;
    for (int base = blockIdx.x * 256; base < N; base += gridDim.x * 256) {
        __syncthreads();
        int i = base + t;
        float a[8] = {0.f, 0.f, 0.f, 0.f, 0.f, 0.f, 0.f, 0.f};
        if (i < N) {
            int dg = deg[i], s0 = start[i];
            int adeg = (dg + 3) & ~3;
            acc8(a, up[i]);
            for (int j = 0; j < adeg; j += 4) {
                uint4 nb = *(const uint4*)(csr + s0 + j);   // 16B-aligned
                uint4 r0 = up[nb.x], r1 = up[nb.y], r2 = up[nb.z], r3 = up[nb.w];
                acc8(a, r0); acc8(a, r1); acc8(a, r2); acc8(a, r3);
            }
            float di = rsqrtf((float)(dg + 1));
            for (int k = 0; k < 7; k++) a[k] *= di;
        }
        #pragma unroll
        for (int k = 0; k < 7; k++) agg[t][k] = a[k];
        __syncthreads();
        int mbase = base + ty * 64;
        for (int mm = 0; mm < 64; mm++) {
            int node = mbase + mm;
            if (node >= N) break;
            const float* ag = agg[ty * 64 + mm];
            float s = b;
            #pragma unroll
            for (int k = 0; k < 7; k++) s += ag[k] * Wsm[k * 64 + lane];
            h[(size_t)node * 64 + lane] = __float2bfloat16(s);
            sum += s; sq += s * s;
        }
    }
    sm[0][ty][lane] = sum;
    sm[1][ty][lane] = sq;
    __syncthreads();
    if (ty == 0) {
        atomicAdd(&stat[lane],      sm[0][0][lane] + sm[0][1][lane] + sm[0][2][lane] + sm[0][3][lane]);
        atomicAdd(&stat[64 + lane], sm[1][0][lane] + sm[1][1][lane] + sm[1][2][lane] + sm[1][3][lane]);
    }
}

// ---- Layer 1 GEMM via MFMA; writes y PAIR-MAJOR: [(c>>4)*NY+node]*16+(c&15)
__global__ __launch_bounds__(256) void k_gemm1(const bf16* h, const float* W,
                                               const float* stat, const float* gam,
                                               const float* bet, const int* deg,
                                               bf16* y, float invN, int N, int NY) {
    __shared__ short Wt[64][72];
    __shared__ float AB[128];
    int t = threadIdx.x, lane = t & 63, ty = t >> 6;
    for (int i = t; i < 4096; i += 256) {
        int k = i >> 6, n = i & 63;
        Wt[n][k] = (short)f2bfbits(W[i]);
    }
    if (t < 64) {
        float mean = stat[t] * invN;
        float var = stat[64 + t] * invN - mean * mean;
        float A = gam[t] * rsqrtf(fmaxf(var, 0.f) + EPS_);
        AB[t] = A;
        AB[64 + t] = bet[t] - mean * A;
    }
    if (blockIdx.x == 0 && t < 64) {     // zero sentinel row N of each pair
        int pr = t >> 4, cl = t & 15;
        y[((size_t)pr * NY + N) * 16 + cl] = __float2bfloat16(0.f);
    }
    __syncthreads();
    int quad = lane >> 4, l16 = lane & 15;
    short8 Bf[2][4];
    #pragma unroll
    for (int kt = 0; kt < 2; kt++)
        #pragma unroll
        for (int nt = 0; nt < 4; nt++) {
            int n = nt * 16 + l16, k0 = kt * 32 + quad * 8;
            Bf[kt][nt] = *(const short8*)&Wt[n][k0];
        }
    int ntile = (N + 63) >> 6;
    for (int tile = blockIdx.x * 4 + ty; tile < ntile; tile += gridDim.x * 4) {
        int base = tile << 6;
        f32x4 acc[4][4];
        #pragma unroll
        for (int a = 0; a < 4; a++)
            #pragma unroll
            for (int b = 0; b < 4; b++) acc[a][b] = (f32x4){0.f, 0.f, 0.f, 0.f};
        #pragma unroll
        for (int kt = 0; kt < 2; kt++) {
            int k0 = kt * 32 + quad * 8;
            float Ak[8], Bk[8];
            #pragma unroll
            for (int j = 0; j < 8; j++) { Ak[j] = AB[k0 + j]; Bk[j] = AB[64 + k0 + j]; }
            #pragma unroll
            for (int mt = 0; mt < 4; mt++) {
                int node = base + mt * 16 + l16;     // tail overread: hbuf padded
                uint4 raw = *(const uint4*)(h + (size_t)node * 64 + k0);
                unsigned rr[4] = {raw.x, raw.y, raw.z, raw.w};
                short8 af;
                #pragma unroll
                for (int j = 0; j < 8; j++) {
                    unsigned bits = (j & 1) ? (rr[j >> 1] & 0xffff0000u)
                                            : (rr[j >> 1] << 16);
                    float v = __uint_as_float(bits);
                    v = fmaxf(v * Ak[j] + Bk[j], 0.f);
                    af[j] = (short)f2bfbits(v);
                }
                #pragma unroll
                for (int nt = 0; nt < 4; nt++)
                    acc[mt][nt] = __builtin_amdgcn_mfma_f32_16x16x32_bf16(
                        af, Bf[kt][nt], acc[mt][nt], 0, 0, 0);
            }
        }
        #pragma unroll
        for (int mt = 0; mt < 4; mt++)
            #pragma unroll
            for (int r = 0; r < 4; r++) {
                int node = base + mt * 16 + quad * 4 + r;
                if (node < N) {
                    float dinv = rsqrtf((float)(deg[node] + 1));
                    #pragma unroll
                    for (int nt = 0; nt < 4; nt++)
                        y[((size_t)nt * NY + node) * 16 + l16] =
                            __float2bfloat16(acc[mt][nt][r] * dinv);
                }
            }
    }
}

// ---- Layer-1 gather: 16-ch pairs, 2-LANE TEAMS (1 L2 request / edge) ---
// Lanes (2i,2i+1) handle one node; parity picks which 16B half of the 32B
// row -> one wave instruction covers both halves on the same 64B line.
__global__ __launch_bounds__(256) void k_gather16(const bf16* y, const int* csr,
                                                  const int* start, const int* deg,
                                                  const float* bias, bf16* h,
                                                  float* stat, int N, int NY) {
    __shared__ float sms[4][2][2][8];    // [ty][par][sum/sq][8ch]
    int t = threadIdx.x, lane = t & 63, ty = t >> 6;
    int team = lane >> 1, par = lane & 1;
    int pair = blockIdx.x & 3;
    int grp = blockIdx.x >> 2;
    int ngrp = gridDim.x >> 2;
    const uint4* yp = (const uint4*)y + (size_t)pair * NY * 2;
    uint4* hp = (uint4*)h + (size_t)pair * NY * 2;
    float b[8];
    #pragma unroll
    for (int k = 0; k < 8; k++) b[k] = bias[pair * 16 + par * 8 + k];
    float sum[8], sq[8];
    #pragma unroll
    for (int k = 0; k < 8; k++) { sum[k] = 0.f; sq[k] = 0.f; }
    for (int i = grp * 128 + ty * 32 + team; i < N; i += ngrp * 128) {
        int dg = deg[i], s0 = start[i];
        int adeg = (dg + 3) & ~3;
        float a[8];
        #pragma unroll
        for (int k = 0; k < 8; k++) a[k] = 0.f;
        acc8(a, yp[2 * i + par]);            // self-loop (team-coalesced 32B)
        for (int j = 0; j < adeg; j += 4) {
            uint4 nb = *(const uint4*)(csr + s0 + j);   // both lanes same addr
            uint4 q0 = yp[2 * nb.x + par];   // team lanes hit same 64B line:
            uint4 q1 = yp[2 * nb.y + par];   // 1 request per edge
            uint4 q2 = yp[2 * nb.z + par];
            uint4 q3 = yp[2 * nb.w + par];
            acc8(a, q0); acc8(a, q1); acc8(a, q2); acc8(a, q3);
        }
        float di = rsqrtf((float)(dg + 1));
        union __align__(16) Pack { bf16 hh[8]; uint4 v; } p;
        #pragma unroll
        for (int k = 0; k < 8; k++) {
            float v = a[k] * di + b[k];
            p.hh[k] = __float2bfloat16(v);
            sum[k] += v; sq[k] += v * v;
        }
        hp[2 * i + par] = p.v;
    }
    #pragma unroll
    for (int k = 0; k < 8; k++) {
        float s1 = sum[k], s2 = sq[k];
        s1 += __shfl_down(s1, 32); s2 += __shfl_down(s2, 32);
        s1 += __shfl_down(s1, 16); s2 += __shfl_down(s2, 16);
        s1 += __shfl_down(s1, 8);  s2 += __shfl_down(s2, 8);
        s1 += __shfl_down(s1, 4);  s2 += __shfl_down(s2, 4);
        s1 += __shfl_down(s1, 2);  s2 += __shfl_down(s2, 2);
        if (lane < 2) { sms[ty][lane][0][k] = s1; sms[ty][lane][1][k] = s2; }
    }
    __syncthreads();
    if (t < 16) {
        int pp = t >> 3, k = t & 7;
        atomicAdd(&stat[pair * 16 + pp * 8 + k],
                  sms[0][pp][0][k] + sms[1][pp][0][k] + sms[2][pp][0][k] + sms[3][pp][0][k]);
    } else if (t >= 64 && t < 80) {
        int q = t - 64, pp = q >> 3, k = q & 7;
        atomicAdd(&stat[64 + pair * 16 + pp * 8 + k],
                  sms[0][pp][1][k] + sms[1][pp][1][k] + sms[2][pp][1][k] + sms[3][pp][1][k]);
    }
}

// ---- Pool: BN1(affine)+ReLU fused; reads h PAIR-MAJOR ------------------
__global__ __launch_bounds__(256) void k_pool(const bf16* h, const float* stat,
                                              const float* gam, const float* bet,
                                              const int* batch, float* pooled,
                                              float* cnt, float invN, int N, int NY) {
    int t = threadIdx.x;
    int lane = t & 63;
    float mean = stat[lane] * invN;
    float var = stat[64 + lane] * invN - mean * mean;
    float A = gam[lane] * rsqrtf(fmaxf(var, 0.f) + EPS_);
    float B = bet[lane] - mean * A;
    size_t pbase = (size_t)(lane >> 4) * NY * 16 + (lane & 15);
    int w = (blockIdx.x * 256 + t) >> 6;
    int nw = (gridDim.x * 256) >> 6;
    int chunk = (N + nw - 1) / nw;
    int i0 = w * chunk;
    int i1 = i0 + chunk;
    if (i1 > N) i1 = N;
    if (i0 >= N) return;
    int curg = batch[i0];
    float acc = 0.f, c = 0.f;
    for (int i = i0; i < i1; i++) {
        int g = batch[i];
        if (g != curg) {
            atomicAdd(&pooled[(size_t)curg * 64 + lane], acc);
            if (lane == 0) atomicAdd(&cnt[curg], c);
            curg = g; acc = 0.f; c = 0.f;
        }
        acc += fmaxf(b2f(h[pbase + (size_t)i * 16]) * A + B, 0.f);
        c += 1.f;
    }
    atomicAdd(&pooled[(size_t)curg * 64 + lane], acc);
    if (lane == 0) atomicAdd(&cnt[curg], c);
}

// ---- Head --------------------------------------------------------------
__global__ __launch_bounds__(64) void k_head(const float* pooled_c, const float* cnt_c,
                                             const float* pooled_s, const float* cnt_s,
                                             const float* Wf1, const float* bf1_,
                                             const float* Wf2, const float* bf2_,
                                             float* out) {
    __shared__ float W1sm[128 * 64];
    __shared__ float W2sm[128];
    int t = threadIdx.x;  // blockDim = 64
    for (int i = t; i < 128 * 64; i += 64) W1sm[i] = Wf1[i];
    for (int i = t; i < 128; i += 64) W2sm[i] = Wf2[i];
    __syncthreads();
    float bb1 = bf1_[t];
    float b20 = bf2_[0];
    float b21 = bf2_[1];
    for (int g = blockIdx.x; g < G_; g += gridDim.x) {
        float ic = 1.f / fmaxf(cnt_c[g], 1.f);
        float is = 1.f / fmaxf(cnt_s[g], 1.f);
        float hc = pooled_c[(size_t)g * 64 + t] * ic;
        float hs = pooled_s[(size_t)g * 64 + t] * is;
        float s = bb1;
        for (int k = 0; k < 64; k++) s += __shfl(hc, k) * W1sm[k * 64 + t];
        for (int k = 0; k < 64; k++) s += __shfl(hs, k) * W1sm[(64 + k) * 64 + t];
        s = fmaxf(s, 0.f);
        float p0 = s * W2sm[t * 2 + 0];
        float p1 = s * W2sm[t * 2 + 1];
        for (int off = 32; off > 0; off >>= 1) {
            p0 += __shfl_down(p0, off);
            p1 += __shfl_down(p1, off);
        }
        if (t == 0) {
            out[g * 2 + 0] = p0 + b20;
            out[g * 2 + 1] = p1 + b21;
        }
    }
}

extern "C" void kernel_launch(void* const* d_in, const int* in_sizes, int n_in,
                              void* d_out, int out_size, void* d_ws, size_t ws_size,
                              hipStream_t stream) {
    float* out = (float*)d_out;

    if (n_in != 26 || in_sizes[0] != NC_ * 7 || in_sizes[1] != 2 * EC_ ||
        in_sizes[2] != NC_ || in_sizes[3] != NS_ * 7 || in_sizes[4] != 2 * ES_ ||
        in_sizes[5] != NS_ || out_size != G_ * 2) {
        k_fillout<<<(out_size + 255) / 256, 256, 0, stream>>>(out, 7777.0f, out_size);
        return;
    }
    if (ws_size < (size_t)WS_REQUIRED) {
        k_fillout<<<(out_size + 255) / 256, 256, 0, stream>>>(
            out, 1000.0f + (float)(ws_size >> 20), out_size);
        return;
    }

    const float* x_c     = (const float*)d_in[0];
    const int*   ei_c    = (const int*)d_in[1];
    const int*   batch_c = (const int*)d_in[2];
    const float* x_s     = (const float*)d_in[3];
    const int*   ei_s    = (const int*)d_in[4];
    const int*   batch_s = (const int*)d_in[5];
    const float* Wc0  = (const float*)d_in[6];
    const float* bc0  = (const float*)d_in[7];
    const float* gc0  = (const float*)d_in[8];
    const float* bec0 = (const float*)d_in[9];
    const float* Wc1  = (const float*)d_in[10];
    const float* bc1  = (const float*)d_in[11];
    const float* gc1  = (const float*)d_in[12];
    const float* bec1 = (const float*)d_in[13];
    const float* Ws0  = (const float*)d_in[14];
    const float* bs0  = (const float*)d_in[15];
    const float* gs0  = (const float*)d_in[16];
    const float* bes0 = (const float*)d_in[17];
    const float* Ws1  = (const float*)d_in[18];
    const float* bs1  = (const float*)d_in[19];
    const float* gs1  = (const float*)d_in[20];
    const float* bes1 = (const float*)d_in[21];
    const float* Wf1  = (const float*)d_in[22];
    const float* bf1_ = (const float*)d_in[23];
    const float* Wf2  = (const float*)d_in[24];
    const float* bf2_ = (const float*)d_in[25];

    const int NYC = NC_ + 8;   // pair-plane stride (chromo), row NC_ = zero sentinel
    const int NYS = NS_ + 8;

    // ---- workspace layout (4-byte words); ~35.0 MB ----
    int* wsw = (int*)d_ws;
    size_t off = 0;
    float* stats_c  = (float*)(wsw + off); off += 256;
    float* stats_s  = (float*)(wsw + off); off += 256;
    float* pooled_c = (float*)(wsw + off); off += (size_t)G_ * 64;
    float* pooled_s = (float*)(wsw + off); off += (size_t)G_ * 64;
    float* cnt_c    = (float*)(wsw + off); off += G_;
    float* cnt_s    = (float*)(wsw + off); off += G_;
    int*   bcnt_c   = wsw + off; off += NB_C;
    int*   bcnt_s   = wsw + off; off += NB_S;
    size_t zero_words = off;
    int*   bbase_c  = wsw + off; off += NB_C + 1;
    int*   bcur_c   = wsw + off; off += NB_C;
    int*   bbase_s  = wsw + off; off += NB_S + 1;
    int*   bcur_s   = wsw + off; off += NB_S;
    int*   deg      = wsw + off; off += NC_;
    int*   start    = wsw + off; off += NC_;
    int*   csr      = wsw + off; off += CSR_WORDS;
    off = (off + 3) & ~(size_t)3;
    bf16*  hbuf     = (bf16*)(wsw + off); off += 3202560;   // row-major N+64 rows / pair-planes
    bf16*  ybuf     = (bf16*)(wsw + off); off += 3200256;   // 4 * NYC * 16 halfwords
    int*   ebuf     = (int*)hbuf;   // ebuf aliases hbuf (dead before gather7 writes h)
    bf16*  ubuf     = ybuf;         // u aliases ybuf (dead before gemm1 writes y)

    k_zero<<<512, 256, 0, stream>>>(wsw, (int)zero_words);

    // ---- CSR prep ----
    k_bhist<<<256, 256, 0, stream>>>(ei_c + EC_, bcnt_c, EC_, NB_C);
    k_bhist<<<256, 256, 0, stream>>>(ei_s + ES_, bcnt_s, ES_, NB_S);
    k_bscan<<<1, 256, 0, stream>>>(bcnt_c, bbase_c, bcur_c, NB_C,
                                   bcnt_s, bbase_s, bcur_s, NB_S);

    // ---- chromo branch ----
    k_bin<<<391, 256, 0, stream>>>(ei_c, ei_c + EC_, bcur_c, ebuf, EC_, NB_C, 4096);
    k_build<<<NB_C, 256, 0, stream>>>(bbase_c, ebuf, x_c, ubuf, deg, start, csr, NC_);
    k_gather7<<<512, 256, 0, stream>>>(ubuf, csr, start, deg, Wc0, bc0, hbuf, stats_c, NC_);
    k_gemm1<<<512, 256, 0, stream>>>(hbuf, Wc1, stats_c, gc0, bec0, deg, ybuf, 1.0f / NC_, NC_, NYC);
    k_gather16<<<3128, 256, 0, stream>>>(ybuf, csr, start, deg, bc1, hbuf, stats_c + 128, NC_, NYC);
    k_pool<<<256, 256, 0, stream>>>(hbuf, stats_c + 128, gc1, bec1, batch_c, pooled_c, cnt_c, 1.0f / NC_, NC_, NYC);

    // ---- solvent branch ----
    k_bin<<<391, 256, 0, stream>>>(ei_s, ei_s + ES_, bcur_s, ebuf, ES_, NB_S, 2048);
    k_build<<<NB_S, 256, 0, stream>>>(bbase_s, ebuf, x_s, ubuf, deg, start, csr, NS_);
    k_gather7<<<256, 256, 0, stream>>>(ubuf, csr, start, deg, Ws0, bs0, hbuf, stats_s, NS_);
    k_gemm1<<<512, 256, 0, stream>>>(hbuf, Ws1, stats_s, gs0, bes0, deg, ybuf, 1.0f / NS_, NS_, NYS);
    k_gather16<<<1564, 256, 0, stream>>>(ybuf, csr, start, deg, bs1, hbuf, stats_s + 128, NS_, NYS);
    k_pool<<<256, 256, 0, stream>>>(hbuf, stats_s + 128, gs1, bes1, batch_s, pooled_s, cnt_s, 1.0f / NS_, NS_, NYS);

    // ---- head ----
    k_head<<<128, 64, 0, stream>>>(pooled_c, cnt_c, pooled_s, cnt_s, Wf1, bf1_, Wf2, bf2_, out);
}

// Round 15
// 423.593 us; speedup vs baseline: 1.7735x; 1.0797x over previous
//
#include <hip/hip_runtime.h>
#include <hip/hip_bf16.h>

typedef __hip_bfloat16 bf16;
typedef __attribute__((ext_vector_type(8))) short short8;
typedef __attribute__((ext_vector_type(4))) float f32x4;

#define NC_ 100000
#define EC_ 1600000
#define NS_ 50000
#define ES_ 800000
#define G_  1024
#define EPS_ 1e-5f

#define NB_C 782          // ceil(100000/128)
#define NB_S 391          // ceil(50000/128)
#define NBMAX 782
#define KSL 16            // LDS slots per bucket in k_bin
#define CSR_WC 2000400    // EC_ + 512*NB_C + 16
#define CSR_WS 1000208    // ES_ + 512*NB_S + 16

#define WS_REQUIRED 39366416ull

__device__ __forceinline__ float b2f(bf16 v) { return __bfloat162float(v); }

__device__ __forceinline__ unsigned short f2bfbits(float v) {
    bf16 b = __float2bfloat16(v);
    union { bf16 b; unsigned short u; } c; c.b = b; return c.u;
}

__device__ __forceinline__ void acc8(float* a, uint4 r) {
    a[0] += __uint_as_float(r.x << 16); a[1] += __uint_as_float(r.x & 0xffff0000u);
    a[2] += __uint_as_float(r.y << 16); a[3] += __uint_as_float(r.y & 0xffff0000u);
    a[4] += __uint_as_float(r.z << 16); a[5] += __uint_as_float(r.z & 0xffff0000u);
    a[6] += __uint_as_float(r.w << 16); a[7] += __uint_as_float(r.w & 0xffff0000u);
}

__global__ void DualGNN_31327491457689_kernel() {}

__global__ __launch_bounds__(256) void k_fillout(float* out, float val, int n) {
    int i = blockIdx.x * 256 + threadIdx.x;
    if (i < n) out[i] = val;
}

__global__ __launch_bounds__(256) void k_zero(int* p, int n) {
    int i = blockIdx.x * 256 + threadIdx.x;
    int stride = gridDim.x * 256;
    while (i < n) { p[i] = 0; i += stride; }
}

// ---- Phase A: bucket histograms, BOTH branches in one launch -----------
__global__ __launch_bounds__(256) void k_bhist2(const int* dst_c, int* bcnt_c,
                                                const int* dst_s, int* bcnt_s) {
    __shared__ int h[NBMAX];
    int t = threadIdx.x;
    const int* dst; int* bcnt; int E, NB, b0, nb;
    if (blockIdx.x < 256) { dst = dst_c; bcnt = bcnt_c; E = EC_; NB = NB_C; b0 = blockIdx.x; nb = 256; }
    else { dst = dst_s; bcnt = bcnt_s; E = ES_; NB = NB_S; b0 = blockIdx.x - 256; nb = 128; }
    for (int i = t; i < NB; i += 256) h[i] = 0;
    __syncthreads();
    for (int e = b0 * 256 + t; e < E; e += nb * 256)
        atomicAdd(&h[dst[e] >> 7], 1);
    __syncthreads();
    for (int i = t; i < NB; i += 256) {
        int v = h[i];
        if (v) atomicAdd(&bcnt[i], v);
    }
}

// ---- Phase B: scan bucket counts (both branches, one block) ------------
__device__ void scan_one(const int* cnt, int* base, int* cur, int NB, int (*sc)[1024]) {
    int t = threadIdx.x;
    for (int i = t; i < 1024; i += 256) sc[0][i] = (i < NB) ? cnt[i] : 0;
    __syncthreads();
    int pin = 0;
    for (int off = 1; off < 1024; off <<= 1) {
        for (int i = t; i < 1024; i += 256) {
            int v = sc[pin][i];
            if (i >= off) v += sc[pin][i - off];
            sc[1 - pin][i] = v;
        }
        __syncthreads();
        pin ^= 1;
    }
    for (int i = t; i <= NB; i += 256) {
        int e = (i == 0) ? 0 : sc[pin][i - 1];
        base[i] = e;
        if (i < NB) cur[i] = e;
    }
    __syncthreads();
}

__global__ __launch_bounds__(256) void k_bscan(const int* cnt_c, int* base_c, int* cur_c, int NBc,
                                               const int* cnt_s, int* base_s, int* cur_s, int NBs) {
    __shared__ int sc[2][1024];
    scan_one(cnt_c, base_c, cur_c, NBc, sc);
    scan_one(cnt_s, base_s, cur_s, NBs, sc);
}

// ---- Phase C: bin packed edges, BOTH branches in one launch ------------
__global__ __launch_bounds__(256) void k_bin2(const int* ei_c, int* bcur_c, int* ebuf_c,
                                              const int* ei_s, int* bcur_s, int* ebuf_s) {
    __shared__ int cnt[NBMAX];
    __shared__ int slot[NBMAX * KSL];
    int t = threadIdx.x;
    const int *src, *dst; int *bcur, *ebuf; int E, NB; int base;
    if (blockIdx.x < 391) {
        src = ei_c; dst = ei_c + EC_; bcur = bcur_c; ebuf = ebuf_c;
        E = EC_; NB = NB_C; base = blockIdx.x * 4096;
    } else {
        src = ei_s; dst = ei_s + ES_; bcur = bcur_s; ebuf = ebuf_s;
        E = ES_; NB = NB_S; base = (blockIdx.x - 391) * 4096;
    }
    if (base >= E) return;
    for (int i = t; i < NB; i += 256) cnt[i] = 0;
    __syncthreads();
    int e1 = base + 4096;
    if (e1 > E) e1 = E;
    for (int e = base + t; e < e1; e += 256) {
        int d = dst[e];
        int p = ((d & 127) << 24) | src[e];
        int b = d >> 7;
        int sl = atomicAdd(&cnt[b], 1);
        if (sl < KSL) slot[b * KSL + sl] = p;
        else { int gp = atomicAdd(&bcur[b], 1); ebuf[gp] = p; }
    }
    __syncthreads();
    for (int b = t; b < NB; b += 256) {
        int c = cnt[b];
        if (c > KSL) c = KSL;
        if (c > 0) {
            int gp = atomicAdd(&bcur[b], c);
            for (int k = 0; k < c; k++) ebuf[gp + k] = slot[b * KSL + k];
        }
    }
}

// ---- Phase D: per-bucket build (both branches), 4-aligned csr + u prep -
__global__ __launch_bounds__(256) void k_build2(const int* bbase_c, const int* ebuf_c,
                                                const float* x_c, bf16* u_c,
                                                int* deg_c, int* start_c, int* csr_c,
                                                const int* bbase_s, const int* ebuf_s,
                                                int* deg_s, int* start_s, int* csr_s) {
    __shared__ int lcnt[128], lofs[128], lcur[128];
    int t = threadIdx.x;
    const int* bbase; const int* ebuf; const float* x; bf16* u;
    int* deg; int* start; int* csr; int N, b;
    if (blockIdx.x < NB_C) {
        b = blockIdx.x; bbase = bbase_c; ebuf = ebuf_c; x = x_c; u = u_c;
        deg = deg_c; start = start_c; csr = csr_c; N = NC_;
    } else {
        b = blockIdx.x - NB_C; bbase = bbase_s; ebuf = ebuf_s; x = 0; u = 0;
        deg = deg_s; start = start_s; csr = csr_s; N = NS_;
    }
    int e0 = bbase[b], e1 = bbase[b + 1];
    int cb = ((e0 + 512 * b) + 3) & ~3;
    int n0 = b << 7;
    if (t < 128) lcnt[t] = 0;
    __syncthreads();
    for (int e = e0 + t; e < e1; e += 256)
        atomicAdd(&lcnt[((unsigned)ebuf[e]) >> 24], 1);
    __syncthreads();
    if (t < 64) {   // exclusive scan of ALIGNED counts, 2 per lane
        int c0 = lcnt[2 * t], c1 = lcnt[2 * t + 1];
        int v0 = (c0 + 3) & ~3, v1 = (c1 + 3) & ~3;
        int s = v0 + v1, incl = s;
        for (int off = 1; off < 64; off <<= 1) {
            int uu = __shfl_up(incl, off);
            if (t >= off) incl += uu;
        }
        int excl = incl - s;
        lofs[2 * t] = excl;
        lofs[2 * t + 1] = excl + v0;
    }
    __syncthreads();
    if (t < 128) {
        int node = n0 + t;
        if (node < N) {
            deg[node] = lcnt[t];
            start[node] = cb + lofs[t];
            if (x) {
                float d = rsqrtf((float)(lcnt[t] + 1));
                union __align__(16) Pack { bf16 hh[8]; uint4 v; } p;
                for (int k = 0; k < 7; k++) p.hh[k] = __float2bfloat16(x[node * 7 + k] * d);
                p.hh[7] = __float2bfloat16(0.f);
                ((uint4*)u)[node] = p.v;
            }
        }
        lcur[t] = lofs[t];
    }
    __syncthreads();
    if (t < 128) {   // sentinel pads (disjoint from scatter range)
        int c = lcnt[t], al = (c + 3) & ~3;
        for (int k = c; k < al; k++) csr[cb + lofs[t] + k] = N;
    }
    for (int e = e0 + t; e < e1; e += 256) {
        unsigned p = (unsigned)ebuf[e];
        int dl = p >> 24;
        int pos = atomicAdd(&lcur[dl], 1);
        csr[cb + pos] = (int)(p & 0xFFFFFF);
    }
    if (b == 0 && t < 4 && u) ((int*)u)[N * 4 + t] = 0;   // zero sentinel row
}

// ---- Solvent u prep (after chromo gather16 frees ybuf) -----------------
__global__ __launch_bounds__(256) void k_prep7(const float* x, const int* deg,
                                               bf16* u, int N) {
    int i = blockIdx.x * 256 + threadIdx.x;
    if (i > N) return;
    union __align__(16) Pack { bf16 hh[8]; uint4 v; } p;
    if (i == N) {
        p.v = (uint4){0u, 0u, 0u, 0u};
    } else {
        float d = rsqrtf((float)(deg[i] + 1));
        for (int k = 0; k < 7; k++) p.hh[k] = __float2bfloat16(x[i * 7 + k] * d);
        p.hh[7] = __float2bfloat16(0.f);
    }
    ((uint4*)u)[i] = p.v;
}

// ---- Layer 0 gather (rank-7) + fused 7x64 GEMM, 2-LANE TEAMS -----------
// Team (2i,2i+1) handles one node; parity splits the edge list.
__global__ __launch_bounds__(256) void k_gather7(const bf16* u, const int* csr,
                                                 const int* start, const int* deg,
                                                 const float* W, const float* bias,
                                                 bf16* h, float* stat, int N) {
    __shared__ float Wsm[7 * 64];
    __shared__ float agg[128][9];
    __shared__ float sm[2][4][64];
    int t = threadIdx.x, lane = t & 63, ty = t >> 6;
    int team = t >> 1, par = t & 1;
    for (int i = t; i < 448; i += 256) Wsm[i] = W[i];
    float b = bias[lane];
    float sum = 0.f, sq = 0.f;
    const uint4* up = (const uint4*)u;
    int i = blockIdx.x * 128 + team;
    float a[8] = {0.f, 0.f, 0.f, 0.f, 0.f, 0.f, 0.f, 0.f};
    if (i < N) {
        int dg = deg[i], s0 = start[i];
        int adeg = (dg + 3) & ~3;
        if (par == 0) acc8(a, up[i]);            // self-loop term
        for (int j = 4 * par; j < adeg; j += 8) {
            uint4 nb = *(const uint4*)(csr + s0 + j);
            uint4 r0 = up[nb.x], r1 = up[nb.y], r2 = up[nb.z], r3 = up[nb.w];
            acc8(a, r0); acc8(a, r1); acc8(a, r2); acc8(a, r3);
        }
    }
    #pragma unroll
    for (int k = 0; k < 7; k++) a[k] += __shfl_xor(a[k], 1);   // combine halves
    if (i < N && par == 0) {
        float di = rsqrtf((float)(deg[i] + 1));
        #pragma unroll
        for (int k = 0; k < 7; k++) agg[team][k] = a[k] * di;
    }
    __syncthreads();
    int mbase = blockIdx.x * 128 + ty * 32;
    for (int mm = 0; mm < 32; mm++) {
        int node = mbase + mm;
        if (node >= N) break;
        const float* ag = agg[ty * 32 + mm];
        float s = b;
        #pragma unroll
        for (int k = 0; k < 7; k++) s += ag[k] * Wsm[k * 64 + lane];
        h[(size_t)node * 64 + lane] = __float2bfloat16(s);
        sum += s; sq += s * s;
    }
    sm[0][ty][lane] = sum;
    sm[1][ty][lane] = sq;
    __syncthreads();
    if (ty == 0) {
        atomicAdd(&stat[lane],      sm[0][0][lane] + sm[0][1][lane] + sm[0][2][lane] + sm[0][3][lane]);
        atomicAdd(&stat[64 + lane], sm[1][0][lane] + sm[1][1][lane] + sm[1][2][lane] + sm[1][3][lane]);
    }
}

// ---- Layer 1 GEMM via MFMA; writes y PAIR-MAJOR: [(c>>4)*NY+node]*16+(c&15)
__global__ __launch_bounds__(256) void k_gemm1(const bf16* h, const float* W,
                                               const float* stat, const float* gam,
                                               const float* bet, const int* deg,
                                               bf16* y, float invN, int N, int NY) {
    __shared__ short Wt[64][72];
    __shared__ float AB[128];
    int t = threadIdx.x, lane = t & 63, ty = t >> 6;
    for (int i = t; i < 4096; i += 256) {
        int k = i >> 6, n = i & 63;
        Wt[n][k] = (short)f2bfbits(W[i]);
    }
    if (t < 64) {
        float mean = stat[t] * invN;
        float var = stat[64 + t] * invN - mean * mean;
        float A = gam[t] * rsqrtf(fmaxf(var, 0.f) + EPS_);
        AB[t] = A;
        AB[64 + t] = bet[t] - mean * A;
    }
    if (blockIdx.x == 0 && t < 64) {     // zero sentinel row N of each pair
        int pr = t >> 4, cl = t & 15;
        y[((size_t)pr * NY + N) * 16 + cl] = __float2bfloat16(0.f);
    }
    __syncthreads();
    int quad = lane >> 4, l16 = lane & 15;
    short8 Bf[2][4];
    #pragma unroll
    for (int kt = 0; kt < 2; kt++)
        #pragma unroll
        for (int nt = 0; nt < 4; nt++) {
            int n = nt * 16 + l16, k0 = kt * 32 + quad * 8;
            Bf[kt][nt] = *(const short8*)&Wt[n][k0];
        }
    int ntile = (N + 63) >> 6;
    for (int tile = blockIdx.x * 4 + ty; tile < ntile; tile += gridDim.x * 4) {
        int base = tile << 6;
        f32x4 acc[4][4];
        #pragma unroll
        for (int a = 0; a < 4; a++)
            #pragma unroll
            for (int b = 0; b < 4; b++) acc[a][b] = (f32x4){0.f, 0.f, 0.f, 0.f};
        #pragma unroll
        for (int kt = 0; kt < 2; kt++) {
            int k0 = kt * 32 + quad * 8;
            float Ak[8], Bk[8];
            #pragma unroll
            for (int j = 0; j < 8; j++) { Ak[j] = AB[k0 + j]; Bk[j] = AB[64 + k0 + j]; }
            #pragma unroll
            for (int mt = 0; mt < 4; mt++) {
                int node = base + mt * 16 + l16;     // tail overread: hbuf padded
                uint4 raw = *(const uint4*)(h + (size_t)node * 64 + k0);
                unsigned rr[4] = {raw.x, raw.y, raw.z, raw.w};
                short8 af;
                #pragma unroll
                for (int j = 0; j < 8; j++) {
                    unsigned bits = (j & 1) ? (rr[j >> 1] & 0xffff0000u)
                                            : (rr[j >> 1] << 16);
                    float v = __uint_as_float(bits);
                    v = fmaxf(v * Ak[j] + Bk[j], 0.f);
                    af[j] = (short)f2bfbits(v);
                }
                #pragma unroll
                for (int nt = 0; nt < 4; nt++)
                    acc[mt][nt] = __builtin_amdgcn_mfma_f32_16x16x32_bf16(
                        af, Bf[kt][nt], acc[mt][nt], 0, 0, 0);
            }
        }
        #pragma unroll
        for (int mt = 0; mt < 4; mt++)
            #pragma unroll
            for (int r = 0; r < 4; r++) {
                int node = base + mt * 16 + quad * 4 + r;
                if (node < N) {
                    float dinv = rsqrtf((float)(deg[node] + 1));
                    #pragma unroll
                    for (int nt = 0; nt < 4; nt++)
                        y[((size_t)nt * NY + node) * 16 + l16] =
                            __float2bfloat16(acc[mt][nt][r] * dinv);
                }
            }
    }
}

// ---- Layer-1 gather: 16-ch pairs, 2-LANE TEAMS (1 L2 request / edge) ---
__global__ __launch_bounds__(256) void k_gather16(const bf16* y, const int* csr,
                                                  const int* start, const int* deg,
                                                  const float* bias, bf16* h,
                                                  float* stat, int N, int NY) {
    __shared__ float sms[4][2][2][8];    // [ty][par][sum/sq][8ch]
    int t = threadIdx.x, lane = t & 63, ty = t >> 6;
    int team = lane >> 1, par = lane & 1;
    int pair = blockIdx.x & 3;
    int grp = blockIdx.x >> 2;
    int ngrp = gridDim.x >> 2;
    const uint4* yp = (const uint4*)y + (size_t)pair * NY * 2;
    uint4* hp = (uint4*)h + (size_t)pair * NY * 2;
    float b[8];
    #pragma unroll
    for (int k = 0; k < 8; k++) b[k] = bias[pair * 16 + par * 8 + k];
    float sum[8], sq[8];
    #pragma unroll
    for (int k = 0; k < 8; k++) { sum[k] = 0.f; sq[k] = 0.f; }
    for (int i = grp * 128 + ty * 32 + team; i < N; i += ngrp * 128) {
        int dg = deg[i], s0 = start[i];
        int adeg = (dg + 3) & ~3;
        float a[8];
        #pragma unroll
        for (int k = 0; k < 8; k++) a[k] = 0.f;
        acc8(a, yp[2 * i + par]);            // self-loop (team-coalesced 32B)
        for (int j = 0; j < adeg; j += 4) {
            uint4 nb = *(const uint4*)(csr + s0 + j);   // both lanes same addr
            uint4 q0 = yp[2 * nb.x + par];   // team lanes hit same 64B line:
            uint4 q1 = yp[2 * nb.y + par];   // 1 request per edge
            uint4 q2 = yp[2 * nb.z + par];
            uint4 q3 = yp[2 * nb.w + par];
            acc8(a, q0); acc8(a, q1); acc8(a, q2); acc8(a, q3);
        }
        float di = rsqrtf((float)(dg + 1));
        union __align__(16) Pack { bf16 hh[8]; uint4 v; } p;
        #pragma unroll
        for (int k = 0; k < 8; k++) {
            float v = a[k] * di + b[k];
            p.hh[k] = __float2bfloat16(v);
            sum[k] += v; sq[k] += v * v;
        }
        hp[2 * i + par] = p.v;
    }
    #pragma unroll
    for (int k = 0; k < 8; k++) {
        float s1 = sum[k], s2 = sq[k];
        s1 += __shfl_down(s1, 32); s2 += __shfl_down(s2, 32);
        s1 += __shfl_down(s1, 16); s2 += __shfl_down(s2, 16);
        s1 += __shfl_down(s1, 8);  s2 += __shfl_down(s2, 8);
        s1 += __shfl_down(s1, 4);  s2 += __shfl_down(s2, 4);
        s1 += __shfl_down(s1, 2);  s2 += __shfl_down(s2, 2);
        if (lane < 2) { sms[ty][lane][0][k] = s1; sms[ty][lane][1][k] = s2; }
    }
    __syncthreads();
    if (t < 16) {
        int pp = t >> 3, k = t & 7;
        atomicAdd(&stat[pair * 16 + pp * 8 + k],
                  sms[0][pp][0][k] + sms[1][pp][0][k] + sms[2][pp][0][k] + sms[3][pp][0][k]);
    } else if (t >= 64 && t < 80) {
        int q = t - 64, pp = q >> 3, k = q & 7;
        atomicAdd(&stat[64 + pair * 16 + pp * 8 + k],
                  sms[0][pp][1][k] + sms[1][pp][1][k] + sms[2][pp][1][k] + sms[3][pp][1][k]);
    }
}

// ---- Pool: BN1(affine)+ReLU fused; reads h PAIR-MAJOR ------------------
__global__ __launch_bounds__(256) void k_pool(const bf16* h, const float* stat,
                                              const float* gam, const float* bet,
                                              const int* batch, float* pooled,
                                              float* cnt, float invN, int N, int NY) {
    int t = threadIdx.x;
    int lane = t & 63;
    float mean = stat[lane] * invN;
    float var = stat[64 + lane] * invN - mean * mean;
    float A = gam[lane] * rsqrtf(fmaxf(var, 0.f) + EPS_);
    float B = bet[lane] - mean * A;
    size_t pbase = (size_t)(lane >> 4) * NY * 16 + (lane & 15);
    int w = (blockIdx.x * 256 + t) >> 6;
    int nw = (gridDim.x * 256) >> 6;
    int chunk = (N + nw - 1) / nw;
    int i0 = w * chunk;
    int i1 = i0 + chunk;
    if (i1 > N) i1 = N;
    if (i0 >= N) return;
    int curg = batch[i0];
    float acc = 0.f, c = 0.f;
    for (int i = i0; i < i1; i++) {
        int g = batch[i];
        if (g != curg) {
            atomicAdd(&pooled[(size_t)curg * 64 + lane], acc);
            if (lane == 0) atomicAdd(&cnt[curg], c);
            curg = g; acc = 0.f; c = 0.f;
        }
        acc += fmaxf(b2f(h[pbase + (size_t)i * 16]) * A + B, 0.f);
        c += 1.f;
    }
    atomicAdd(&pooled[(size_t)curg * 64 + lane], acc);
    if (lane == 0) atomicAdd(&cnt[curg], c);
}

// ---- Head --------------------------------------------------------------
__global__ __launch_bounds__(64) void k_head(const float* pooled_c, const float* cnt_c,
                                             const float* pooled_s, const float* cnt_s,
                                             const float* Wf1, const float* bf1_,
                                             const float* Wf2, const float* bf2_,
                                             float* out) {
    __shared__ float W1sm[128 * 64];
    __shared__ float W2sm[128];
    int t = threadIdx.x;  // blockDim = 64
    for (int i = t; i < 128 * 64; i += 64) W1sm[i] = Wf1[i];
    for (int i = t; i < 128; i += 64) W2sm[i] = Wf2[i];
    __syncthreads();
    float bb1 = bf1_[t];
    float b20 = bf2_[0];
    float b21 = bf2_[1];
    for (int g = blockIdx.x; g < G_; g += gridDim.x) {
        float ic = 1.f / fmaxf(cnt_c[g], 1.f);
        float is = 1.f / fmaxf(cnt_s[g], 1.f);
        float hc = pooled_c[(size_t)g * 64 + t] * ic;
        float hs = pooled_s[(size_t)g * 64 + t] * is;
        float s = bb1;
        for (int k = 0; k < 64; k++) s += __shfl(hc, k) * W1sm[k * 64 + t];
        for (int k = 0; k < 64; k++) s += __shfl(hs, k) * W1sm[(64 + k) * 64 + t];
        s = fmaxf(s, 0.f);
        float p0 = s * W2sm[t * 2 + 0];
        float p1 = s * W2sm[t * 2 + 1];
        for (int off = 32; off > 0; off >>= 1) {
            p0 += __shfl_down(p0, off);
            p1 += __shfl_down(p1, off);
        }
        if (t == 0) {
            out[g * 2 + 0] = p0 + b20;
            out[g * 2 + 1] = p1 + b21;
        }
    }
}

extern "C" void kernel_launch(void* const* d_in, const int* in_sizes, int n_in,
                              void* d_out, int out_size, void* d_ws, size_t ws_size,
                              hipStream_t stream) {
    float* out = (float*)d_out;

    if (n_in != 26 || in_sizes[0] != NC_ * 7 || in_sizes[1] != 2 * EC_ ||
        in_sizes[2] != NC_ || in_sizes[3] != NS_ * 7 || in_sizes[4] != 2 * ES_ ||
        in_sizes[5] != NS_ || out_size != G_ * 2) {
        k_fillout<<<(out_size + 255) / 256, 256, 0, stream>>>(out, 7777.0f, out_size);
        return;
    }
    if (ws_size < (size_t)WS_REQUIRED) {
        k_fillout<<<(out_size + 255) / 256, 256, 0, stream>>>(
            out, 1000.0f + (float)(ws_size >> 20), out_size);
        return;
    }

    const float* x_c     = (const float*)d_in[0];
    const int*   ei_c    = (const int*)d_in[1];
    const int*   batch_c = (const int*)d_in[2];
    const float* x_s     = (const float*)d_in[3];
    const int*   ei_s    = (const int*)d_in[4];
    const int*   batch_s = (const int*)d_in[5];
    const float* Wc0  = (const float*)d_in[6];
    const float* bc0  = (const float*)d_in[7];
    const float* gc0  = (const float*)d_in[8];
    const float* bec0 = (const float*)d_in[9];
    const float* Wc1  = (const float*)d_in[10];
    const float* bc1  = (const float*)d_in[11];
    const float* gc1  = (const float*)d_in[12];
    const float* bec1 = (const float*)d_in[13];
    const float* Ws0  = (const float*)d_in[14];
    const float* bs0  = (const float*)d_in[15];
    const float* gs0  = (const float*)d_in[16];
    const float* bes0 = (const float*)d_in[17];
    const float* Ws1  = (const float*)d_in[18];
    const float* bs1  = (const float*)d_in[19];
    const float* gs1  = (const float*)d_in[20];
    const float* bes1 = (const float*)d_in[21];
    const float* Wf1  = (const float*)d_in[22];
    const float* bf1_ = (const float*)d_in[23];
    const float* Wf2  = (const float*)d_in[24];
    const float* bf2_ = (const float*)d_in[25];

    const int NYC = NC_ + 8;   // pair-plane stride, row N = zero sentinel
    const int NYS = NS_ + 8;

    // ---- workspace layout (4-byte words); 39,366,416 B ----
    int* wsw = (int*)d_ws;
    size_t off = 0;
    float* stats_c  = (float*)(wsw + off); off += 256;
    float* stats_s  = (float*)(wsw + off); off += 256;
    float* pooled_c = (float*)(wsw + off); off += (size_t)G_ * 64;
    float* pooled_s = (float*)(wsw + off); off += (size_t)G_ * 64;
    float* cnt_c    = (float*)(wsw + off); off += G_;
    float* cnt_s    = (float*)(wsw + off); off += G_;
    int*   bcnt_c   = wsw + off; off += NB_C;
    int*   bcnt_s   = wsw + off; off += NB_S;
    size_t zero_words = off;
    int*   bbase_c  = wsw + off; off += NB_C + 1;
    int*   bcur_c   = wsw + off; off += NB_C;
    int*   bbase_s  = wsw + off; off += NB_S + 1;
    int*   bcur_s   = wsw + off; off += NB_S;
    int*   deg_c    = wsw + off; off += NC_;
    int*   start_c  = wsw + off; off += NC_;
    int*   deg_s    = wsw + off; off += NS_;
    int*   start_s  = wsw + off; off += NS_;
    int*   csr_c    = wsw + off; off += CSR_WC;
    int*   csr_s    = wsw + off; off += CSR_WS;
    off = (off + 3) & ~(size_t)3;
    bf16*  hbuf     = (bf16*)(wsw + off); off += 3202560;   // also holds ebuf_c/ebuf_s
    bf16*  ybuf     = (bf16*)(wsw + off); off += 3200256;   // also holds u_c / u_s
    off += 1024;   // tail pad: k_gemm1 last-tile overread
    int*   ebuf_c   = (int*)hbuf;                 // dead before gather7 writes h
    int*   ebuf_s   = (int*)hbuf + 1600000;
    bf16*  u_c      = ybuf;                       // dead before gemm1 writes y
    bf16*  u_s      = ybuf;                       // written later by k_prep7

    k_zero<<<512, 256, 0, stream>>>(wsw, (int)zero_words);

    // ---- CSR prep (both branches per launch) ----
    k_bhist2<<<384, 256, 0, stream>>>(ei_c + EC_, bcnt_c, ei_s + ES_, bcnt_s);
    k_bscan<<<1, 256, 0, stream>>>(bcnt_c, bbase_c, bcur_c, NB_C,
                                   bcnt_s, bbase_s, bcur_s, NB_S);
    k_bin2<<<587, 256, 0, stream>>>(ei_c, bcur_c, ebuf_c, ei_s, bcur_s, ebuf_s);
    k_build2<<<NB_C + NB_S, 256, 0, stream>>>(bbase_c, ebuf_c, x_c, u_c,
                                              deg_c, start_c, csr_c,
                                              bbase_s, ebuf_s,
                                              deg_s, start_s, csr_s);

    // ---- chromo branch ----
    k_gather7<<<782, 256, 0, stream>>>(u_c, csr_c, start_c, deg_c, Wc0, bc0, hbuf, stats_c, NC_);
    k_gemm1<<<512, 256, 0, stream>>>(hbuf, Wc1, stats_c, gc0, bec0, deg_c, ybuf, 1.0f / NC_, NC_, NYC);
    k_gather16<<<3128, 256, 0, stream>>>(ybuf, csr_c, start_c, deg_c, bc1, hbuf, stats_c + 128, NC_, NYC);
    k_pool<<<256, 256, 0, stream>>>(hbuf, stats_c + 128, gc1, bec1, batch_c, pooled_c, cnt_c, 1.0f / NC_, NC_, NYC);

    // ---- solvent branch (ybuf/hbuf freed by chromo) ----
    k_prep7<<<(NS_ + 256) / 256, 256, 0, stream>>>(x_s, deg_s, u_s, NS_);
    k_gather7<<<391, 256, 0, stream>>>(u_s, csr_s, start_s, deg_s, Ws0, bs0, hbuf, stats_s, NS_);
    k_gemm1<<<512, 256, 0, stream>>>(hbuf, Ws1, stats_s, gs0, bes0, deg_s, ybuf, 1.0f / NS_, NS_, NYS);
    k_gather16<<<1564, 256, 0, stream>>>(ybuf, csr_s, start_s, deg_s, bs1, hbuf, stats_s + 128, NS_, NYS);
    k_pool<<<256, 256, 0, stream>>>(hbuf, stats_s + 128, gs1, bes1, batch_s, pooled_s, cnt_s, 1.0f / NS_, NS_, NYS);

    // ---- head ----
    k_head<<<128, 64, 0, stream>>>(pooled_c, cnt_c, pooled_s, cnt_s, Wf1, bf1_, Wf2, bf2_, out);
}

// Round 16
// 391.144 us; speedup vs baseline: 1.9207x; 1.0830x over previous
//
#include <hip/hip_runtime.h>
#include <hip/hip_bf16.h>

typedef __hip_bfloat16 bf16;
typedef __attribute__((ext_vector_type(8))) short short8;
typedef __attribute__((ext_vector_type(4))) float f32x4;

#define NC_ 100000
#define EC_ 1600000
#define NS_ 50000
#define ES_ 800000
#define G_  1024
#define EPS_ 1e-5f

#define NB_C 782
#define NB_S 391
#define NBMAX 782
#define KSL 16
#define CSR_WC 2000400    // EC_ + 512*NB_C + 16
#define CSR_WS 1000208    // ES_ + 512*NB_S + 16

#define WS_MIN_FALLBACK 39356176ull
#define WS_BIG          52163344ull

__device__ __forceinline__ float b2f(bf16 v) { return __bfloat162float(v); }

__device__ __forceinline__ unsigned short f2bfbits(float v) {
    bf16 b = __float2bfloat16(v);
    union { bf16 b; unsigned short u; } c; c.b = b; return c.u;
}

__device__ __forceinline__ void acc8(float* a, uint4 r) {
    a[0] += __uint_as_float(r.x << 16); a[1] += __uint_as_float(r.x & 0xffff0000u);
    a[2] += __uint_as_float(r.y << 16); a[3] += __uint_as_float(r.y & 0xffff0000u);
    a[4] += __uint_as_float(r.z << 16); a[5] += __uint_as_float(r.z & 0xffff0000u);
    a[6] += __uint_as_float(r.w << 16); a[7] += __uint_as_float(r.w & 0xffff0000u);
}

__global__ void DualGNN_31327491457689_kernel() {}

__global__ __launch_bounds__(256) void k_fillout(float* out, float val, int n) {
    int i = blockIdx.x * 256 + threadIdx.x;
    if (i < n) out[i] = val;
}

__global__ __launch_bounds__(256) void k_zero(int* p, int n) {
    int i = blockIdx.x * 256 + threadIdx.x;
    int stride = gridDim.x * 256;
    while (i < n) { p[i] = 0; i += stride; }
}

// ---- Phase A: bucket histograms, both branches -------------------------
__global__ __launch_bounds__(256) void k_bhist2(const int* dst_c, int* bcnt_c,
                                                const int* dst_s, int* bcnt_s) {
    __shared__ int h[NBMAX];
    int t = threadIdx.x;
    const int* dst; int* bcnt; int E, NB, b0, nb;
    if (blockIdx.x < 256) { dst = dst_c; bcnt = bcnt_c; E = EC_; NB = NB_C; b0 = blockIdx.x; nb = 256; }
    else { dst = dst_s; bcnt = bcnt_s; E = ES_; NB = NB_S; b0 = blockIdx.x - 256; nb = 128; }
    for (int i = t; i < NB; i += 256) h[i] = 0;
    __syncthreads();
    for (int e = b0 * 256 + t; e < E; e += nb * 256)
        atomicAdd(&h[dst[e] >> 7], 1);
    __syncthreads();
    for (int i = t; i < NB; i += 256) {
        int v = h[i];
        if (v) atomicAdd(&bcnt[i], v);
    }
}

// ---- Phase B: scan bucket counts ---------------------------------------
__device__ void scan_one(const int* cnt, int* base, int* cur, int NB, int (*sc)[1024]) {
    int t = threadIdx.x;
    for (int i = t; i < 1024; i += 256) sc[0][i] = (i < NB) ? cnt[i] : 0;
    __syncthreads();
    int pin = 0;
    for (int off = 1; off < 1024; off <<= 1) {
        for (int i = t; i < 1024; i += 256) {
            int v = sc[pin][i];
            if (i >= off) v += sc[pin][i - off];
            sc[1 - pin][i] = v;
        }
        __syncthreads();
        pin ^= 1;
    }
    for (int i = t; i <= NB; i += 256) {
        int e = (i == 0) ? 0 : sc[pin][i - 1];
        base[i] = e;
        if (i < NB) cur[i] = e;
    }
    __syncthreads();
}

__global__ __launch_bounds__(256) void k_bscan(const int* cnt_c, int* base_c, int* cur_c, int NBc,
                                               const int* cnt_s, int* base_s, int* cur_s, int NBs) {
    __shared__ int sc[2][1024];
    scan_one(cnt_c, base_c, cur_c, NBc, sc);
    scan_one(cnt_s, base_s, cur_s, NBs, sc);
}

// ---- Phase C: bin packed edges -----------------------------------------
__global__ __launch_bounds__(256) void k_bin2(const int* ei_c, int* bcur_c, int* ebuf_c,
                                              const int* ei_s, int* bcur_s, int* ebuf_s) {
    __shared__ int cnt[NBMAX];
    __shared__ int slot[NBMAX * KSL];
    int t = threadIdx.x;
    const int *src, *dst; int *bcur, *ebuf; int E, NB; int base;
    if (blockIdx.x < 391) {
        src = ei_c; dst = ei_c + EC_; bcur = bcur_c; ebuf = ebuf_c;
        E = EC_; NB = NB_C; base = blockIdx.x * 4096;
    } else {
        src = ei_s; dst = ei_s + ES_; bcur = bcur_s; ebuf = ebuf_s;
        E = ES_; NB = NB_S; base = (blockIdx.x - 391) * 4096;
    }
    if (base >= E) return;
    for (int i = t; i < NB; i += 256) cnt[i] = 0;
    __syncthreads();
    int e1 = base + 4096;
    if (e1 > E) e1 = E;
    for (int e = base + t; e < e1; e += 256) {
        int d = dst[e];
        int p = ((d & 127) << 24) | src[e];
        int b = d >> 7;
        int sl = atomicAdd(&cnt[b], 1);
        if (sl < KSL) slot[b * KSL + sl] = p;
        else { int gp = atomicAdd(&bcur[b], 1); ebuf[gp] = p; }
    }
    __syncthreads();
    for (int b = t; b < NB; b += 256) {
        int c = cnt[b];
        if (c > KSL) c = KSL;
        if (c > 0) {
            int gp = atomicAdd(&bcur[b], c);
            for (int k = 0; k < c; k++) ebuf[gp + k] = slot[b * KSL + k];
        }
    }
}

// ---- Phase D: per-bucket build + u prep (both branches) ----------------
__global__ __launch_bounds__(256) void k_build2(const int* bbase_c, const int* ebuf_c,
                                                const float* x_c, bf16* u_c,
                                                int* deg_c, int* start_c, int* csr_c,
                                                const int* bbase_s, const int* ebuf_s,
                                                const float* x_s, bf16* u_s,
                                                int* deg_s, int* start_s, int* csr_s) {
    __shared__ int lcnt[128], lofs[128], lcur[128];
    int t = threadIdx.x;
    const int* bbase; const int* ebuf; const float* x; bf16* u;
    int* deg; int* start; int* csr; int N, b;
    if (blockIdx.x < NB_C) {
        b = blockIdx.x; bbase = bbase_c; ebuf = ebuf_c; x = x_c; u = u_c;
        deg = deg_c; start = start_c; csr = csr_c; N = NC_;
    } else {
        b = blockIdx.x - NB_C; bbase = bbase_s; ebuf = ebuf_s; x = x_s; u = u_s;
        deg = deg_s; start = start_s; csr = csr_s; N = NS_;
    }
    int e0 = bbase[b], e1 = bbase[b + 1];
    int cb = ((e0 + 512 * b) + 3) & ~3;
    int n0 = b << 7;
    if (t < 128) lcnt[t] = 0;
    __syncthreads();
    for (int e = e0 + t; e < e1; e += 256)
        atomicAdd(&lcnt[((unsigned)ebuf[e]) >> 24], 1);
    __syncthreads();
    if (t < 64) {
        int c0 = lcnt[2 * t], c1 = lcnt[2 * t + 1];
        int v0 = (c0 + 3) & ~3, v1 = (c1 + 3) & ~3;
        int s = v0 + v1, incl = s;
        for (int off = 1; off < 64; off <<= 1) {
            int uu = __shfl_up(incl, off);
            if (t >= off) incl += uu;
        }
        int excl = incl - s;
        lofs[2 * t] = excl;
        lofs[2 * t + 1] = excl + v0;
    }
    __syncthreads();
    if (t < 128) {
        int node = n0 + t;
        if (node < N) {
            deg[node] = lcnt[t];
            start[node] = cb + lofs[t];
            if (x) {
                float d = rsqrtf((float)(lcnt[t] + 1));
                union __align__(16) Pack { bf16 hh[8]; uint4 v; } p;
                for (int k = 0; k < 7; k++) p.hh[k] = __float2bfloat16(x[node * 7 + k] * d);
                p.hh[7] = __float2bfloat16(0.f);
                ((uint4*)u)[node] = p.v;
            }
        }
        lcur[t] = lofs[t];
    }
    __syncthreads();
    if (t < 128) {
        int c = lcnt[t], al = (c + 3) & ~3;
        for (int k = c; k < al; k++) csr[cb + lofs[t] + k] = N;
    }
    for (int e = e0 + t; e < e1; e += 256) {
        unsigned p = (unsigned)ebuf[e];
        int dl = p >> 24;
        int pos = atomicAdd(&lcur[dl], 1);
        csr[cb + pos] = (int)(p & 0xFFFFFF);
    }
    if (b == 0 && t < 4 && u && x) ((int*)u)[N * 4 + t] = 0;   // zero sentinel row
}

// ---- u prep (fallback path only) ---------------------------------------
__global__ __launch_bounds__(256) void k_prep7(const float* x, const int* deg,
                                               bf16* u, int N) {
    int i = blockIdx.x * 256 + threadIdx.x;
    if (i > N) return;
    union __align__(16) Pack { bf16 hh[8]; uint4 v; } p;
    if (i == N) {
        p.v = (uint4){0u, 0u, 0u, 0u};
    } else {
        float d = rsqrtf((float)(deg[i] + 1));
        for (int k = 0; k < 7; k++) p.hh[k] = __float2bfloat16(x[i * 7 + k] * d);
        p.hh[7] = __float2bfloat16(0.f);
    }
    ((uint4*)u)[i] = p.v;
}

// ---- Layer 0 gather (rank-7) + fused 7x64 GEMM, 2-lane teams, merged ---
__global__ __launch_bounds__(256) void k_gather7m(
    const bf16* u_c, const int* csr_c, const int* start_c, const int* deg_c,
    const float* W_c, const float* bias_c, bf16* h_c, float* stat_c, int N_c,
    const bf16* u_s, const int* csr_s, const int* start_s, const int* deg_s,
    const float* W_s, const float* bias_s, bf16* h_s, float* stat_s, int N_s,
    int nblk_c) {
    __shared__ float Wsm[7 * 64];
    __shared__ float agg[128][9];
    __shared__ float sm[2][4][64];
    const bf16* u; const int *csr, *start, *deg; const float *W, *bias;
    bf16* h; float* stat; int N, lb;
    if ((int)blockIdx.x < nblk_c) {
        lb = blockIdx.x; u = u_c; csr = csr_c; start = start_c; deg = deg_c;
        W = W_c; bias = bias_c; h = h_c; stat = stat_c; N = N_c;
    } else {
        lb = blockIdx.x - nblk_c; u = u_s; csr = csr_s; start = start_s; deg = deg_s;
        W = W_s; bias = bias_s; h = h_s; stat = stat_s; N = N_s;
    }
    int t = threadIdx.x, lane = t & 63, ty = t >> 6;
    int team = t >> 1, par = t & 1;
    for (int i = t; i < 448; i += 256) Wsm[i] = W[i];
    float b = bias[lane];
    float sum = 0.f, sq = 0.f;
    const uint4* up = (const uint4*)u;
    int i = lb * 128 + team;
    float a[8] = {0.f, 0.f, 0.f, 0.f, 0.f, 0.f, 0.f, 0.f};
    if (i < N) {
        int dg = deg[i], s0 = start[i];
        int adeg = (dg + 3) & ~3;
        if (par == 0) acc8(a, up[i]);            // self-loop term
        for (int j = 4 * par; j < adeg; j += 8) {
            uint4 nb = *(const uint4*)(csr + s0 + j);
            uint4 r0 = up[nb.x], r1 = up[nb.y], r2 = up[nb.z], r3 = up[nb.w];
            acc8(a, r0); acc8(a, r1); acc8(a, r2); acc8(a, r3);
        }
    }
    #pragma unroll
    for (int k = 0; k < 7; k++) a[k] += __shfl_xor(a[k], 1);   // combine halves
    if (i < N && par == 0) {
        float di = rsqrtf((float)(deg[i] + 1));
        #pragma unroll
        for (int k = 0; k < 7; k++) agg[team][k] = a[k] * di;
    }
    __syncthreads();
    int mbase = lb * 128 + ty * 32;
    for (int mm = 0; mm < 32; mm++) {
        int node = mbase + mm;
        if (node >= N) break;
        const float* ag = agg[ty * 32 + mm];
        float s = b;
        #pragma unroll
        for (int k = 0; k < 7; k++) s += ag[k] * Wsm[k * 64 + lane];
        h[(size_t)node * 64 + lane] = __float2bfloat16(s);
        sum += s; sq += s * s;
    }
    sm[0][ty][lane] = sum;
    sm[1][ty][lane] = sq;
    __syncthreads();
    if (ty == 0) {
        atomicAdd(&stat[lane],      sm[0][0][lane] + sm[0][1][lane] + sm[0][2][lane] + sm[0][3][lane]);
        atomicAdd(&stat[64 + lane], sm[1][0][lane] + sm[1][1][lane] + sm[1][2][lane] + sm[1][3][lane]);
    }
}

// ---- Layer 1 GEMM via MFMA, merged; y PAIR-MAJOR -----------------------
__global__ __launch_bounds__(256) void k_gemm1m(
    const bf16* h_c, const float* W_c, const float* stat_c, const float* gam_c,
    const float* bet_c, const int* deg_c, bf16* y_c, float invN_c, int N_c, int NY_c,
    const bf16* h_s, const float* W_s, const float* stat_s, const float* gam_s,
    const float* bet_s, const int* deg_s, bf16* y_s, float invN_s, int N_s, int NY_s,
    int nblk_c) {
    __shared__ short Wt[64][72];
    __shared__ float AB[128];
    const bf16* h; const float *W, *stat, *gam, *bet; const int* deg;
    bf16* y; float invN; int N, NY, lb, nb;
    if ((int)blockIdx.x < nblk_c) {
        lb = blockIdx.x; nb = nblk_c;
        h = h_c; W = W_c; stat = stat_c; gam = gam_c; bet = bet_c; deg = deg_c;
        y = y_c; invN = invN_c; N = N_c; NY = NY_c;
    } else {
        lb = blockIdx.x - nblk_c; nb = gridDim.x - nblk_c;
        h = h_s; W = W_s; stat = stat_s; gam = gam_s; bet = bet_s; deg = deg_s;
        y = y_s; invN = invN_s; N = N_s; NY = NY_s;
    }
    int t = threadIdx.x, lane = t & 63, ty = t >> 6;
    for (int i = t; i < 4096; i += 256) {
        int k = i >> 6, n = i & 63;
        Wt[n][k] = (short)f2bfbits(W[i]);
    }
    if (t < 64) {
        float mean = stat[t] * invN;
        float var = stat[64 + t] * invN - mean * mean;
        float A = gam[t] * rsqrtf(fmaxf(var, 0.f) + EPS_);
        AB[t] = A;
        AB[64 + t] = bet[t] - mean * A;
    }
    if (lb == 0 && t < 64) {     // zero sentinel row N of each pair
        int pr = t >> 4, cl = t & 15;
        y[((size_t)pr * NY + N) * 16 + cl] = __float2bfloat16(0.f);
    }
    __syncthreads();
    int quad = lane >> 4, l16 = lane & 15;
    short8 Bf[2][4];
    #pragma unroll
    for (int kt = 0; kt < 2; kt++)
        #pragma unroll
        for (int nt = 0; nt < 4; nt++) {
            int n = nt * 16 + l16, k0 = kt * 32 + quad * 8;
            Bf[kt][nt] = *(const short8*)&Wt[n][k0];
        }
    int ntile = (N + 63) >> 6;
    for (int tile = lb * 4 + ty; tile < ntile; tile += nb * 4) {
        int base = tile << 6;
        f32x4 acc[4][4];
        #pragma unroll
        for (int a = 0; a < 4; a++)
            #pragma unroll
            for (int b = 0; b < 4; b++) acc[a][b] = (f32x4){0.f, 0.f, 0.f, 0.f};
        #pragma unroll
        for (int kt = 0; kt < 2; kt++) {
            int k0 = kt * 32 + quad * 8;
            float Ak[8], Bk[8];
            #pragma unroll
            for (int j = 0; j < 8; j++) { Ak[j] = AB[k0 + j]; Bk[j] = AB[64 + k0 + j]; }
            #pragma unroll
            for (int mt = 0; mt < 4; mt++) {
                int node = base + mt * 16 + l16;     // tail overread: h padded
                uint4 raw = *(const uint4*)(h + (size_t)node * 64 + k0);
                unsigned rr[4] = {raw.x, raw.y, raw.z, raw.w};
                short8 af;
                #pragma unroll
                for (int j = 0; j < 8; j++) {
                    unsigned bits = (j & 1) ? (rr[j >> 1] & 0xffff0000u)
                                            : (rr[j >> 1] << 16);
                    float v = __uint_as_float(bits);
                    v = fmaxf(v * Ak[j] + Bk[j], 0.f);
                    af[j] = (short)f2bfbits(v);
                }
                #pragma unroll
                for (int nt = 0; nt < 4; nt++)
                    acc[mt][nt] = __builtin_amdgcn_mfma_f32_16x16x32_bf16(
                        af, Bf[kt][nt], acc[mt][nt], 0, 0, 0);
            }
        }
        #pragma unroll
        for (int mt = 0; mt < 4; mt++)
            #pragma unroll
            for (int r = 0; r < 4; r++) {
                int node = base + mt * 16 + quad * 4 + r;
                if (node < N) {
                    float dinv = rsqrtf((float)(deg[node] + 1));
                    #pragma unroll
                    for (int nt = 0; nt < 4; nt++)
                        y[((size_t)nt * NY + node) * 16 + l16] =
                            __float2bfloat16(acc[mt][nt][r] * dinv);
                }
            }
    }
}

// ---- Layer-1 gather: 16-ch pairs, 2-lane teams (1 L2 request / edge) ---
__global__ __launch_bounds__(256) void k_gather16(const bf16* y, const int* csr,
                                                  const int* start, const int* deg,
                                                  const float* bias, bf16* h,
                                                  float* stat, int N, int NY) {
    __shared__ float sms[4][2][2][8];
    int t = threadIdx.x, lane = t & 63, ty = t >> 6;
    int team = lane >> 1, par = lane & 1;
    int pair = blockIdx.x & 3;
    int grp = blockIdx.x >> 2;
    int ngrp = gridDim.x >> 2;
    const uint4* yp = (const uint4*)y + (size_t)pair * NY * 2;
    uint4* hp = (uint4*)h + (size_t)pair * NY * 2;
    float b[8];
    #pragma unroll
    for (int k = 0; k < 8; k++) b[k] = bias[pair * 16 + par * 8 + k];
    float sum[8], sq[8];
    #pragma unroll
    for (int k = 0; k < 8; k++) { sum[k] = 0.f; sq[k] = 0.f; }
    for (int i = grp * 128 + ty * 32 + team; i < N; i += ngrp * 128) {
        int dg = deg[i], s0 = start[i];
        int adeg = (dg + 3) & ~3;
        float a[8];
        #pragma unroll
        for (int k = 0; k < 8; k++) a[k] = 0.f;
        acc8(a, yp[2 * i + par]);
        for (int j = 0; j < adeg; j += 4) {
            uint4 nb = *(const uint4*)(csr + s0 + j);
            uint4 q0 = yp[2 * nb.x + par];
            uint4 q1 = yp[2 * nb.y + par];
            uint4 q2 = yp[2 * nb.z + par];
            uint4 q3 = yp[2 * nb.w + par];
            acc8(a, q0); acc8(a, q1); acc8(a, q2); acc8(a, q3);
        }
        float di = rsqrtf((float)(dg + 1));
        union __align__(16) Pack { bf16 hh[8]; uint4 v; } p;
        #pragma unroll
        for (int k = 0; k < 8; k++) {
            float v = a[k] * di + b[k];
            p.hh[k] = __float2bfloat16(v);
            sum[k] += v; sq[k] += v * v;
        }
        hp[2 * i + par] = p.v;
    }
    #pragma unroll
    for (int k = 0; k < 8; k++) {
        float s1 = sum[k], s2 = sq[k];
        s1 += __shfl_down(s1, 32); s2 += __shfl_down(s2, 32);
        s1 += __shfl_down(s1, 16); s2 += __shfl_down(s2, 16);
        s1 += __shfl_down(s1, 8);  s2 += __shfl_down(s2, 8);
        s1 += __shfl_down(s1, 4);  s2 += __shfl_down(s2, 4);
        s1 += __shfl_down(s1, 2);  s2 += __shfl_down(s2, 2);
        if (lane < 2) { sms[ty][lane][0][k] = s1; sms[ty][lane][1][k] = s2; }
    }
    __syncthreads();
    if (t < 16) {
        int pp = t >> 3, k = t & 7;
        atomicAdd(&stat[pair * 16 + pp * 8 + k],
                  sms[0][pp][0][k] + sms[1][pp][0][k] + sms[2][pp][0][k] + sms[3][pp][0][k]);
    } else if (t >= 64 && t < 80) {
        int q = t - 64, pp = q >> 3, k = q & 7;
        atomicAdd(&stat[64 + pair * 16 + pp * 8 + k],
                  sms[0][pp][1][k] + sms[1][pp][1][k] + sms[2][pp][1][k] + sms[3][pp][1][k]);
    }
}

// ---- Pool merged: BN1+ReLU fused; reads h PAIR-MAJOR -------------------
__global__ __launch_bounds__(256) void k_poolm(
    const bf16* h_c, const float* stat_c, const float* gam_c, const float* bet_c,
    const int* batch_c, float* pooled_c, float* cnt_c, float invN_c, int N_c, int NY_c,
    const bf16* h_s, const float* stat_s, const float* gam_s, const float* bet_s,
    const int* batch_s, float* pooled_s, float* cnt_s, float invN_s, int N_s, int NY_s,
    int nblk_c) {
    const bf16* h; const float *stat, *gam, *bet; const int* batch;
    float *pooled, *cnt; float invN; int N, NY, lb, nb;
    if ((int)blockIdx.x < nblk_c) {
        lb = blockIdx.x; nb = nblk_c;
        h = h_c; stat = stat_c; gam = gam_c; bet = bet_c; batch = batch_c;
        pooled = pooled_c; cnt = cnt_c; invN = invN_c; N = N_c; NY = NY_c;
    } else {
        lb = blockIdx.x - nblk_c; nb = gridDim.x - nblk_c;
        h = h_s; stat = stat_s; gam = gam_s; bet = bet_s; batch = batch_s;
        pooled = pooled_s; cnt = cnt_s; invN = invN_s; N = N_s; NY = NY_s;
    }
    int t = threadIdx.x;
    int lane = t & 63;
    float mean = stat[lane] * invN;
    float var = stat[64 + lane] * invN - mean * mean;
    float A = gam[lane] * rsqrtf(fmaxf(var, 0.f) + EPS_);
    float B = bet[lane] - mean * A;
    size_t pbase = (size_t)(lane >> 4) * NY * 16 + (lane & 15);
    int w = (lb * 256 + t) >> 6;
    int nw = nb * 4;
    int chunk = (N + nw - 1) / nw;
    int i0 = w * chunk;
    int i1 = i0 + chunk;
    if (i1 > N) i1 = N;
    if (i0 >= N) return;
    int curg = batch[i0];
    float acc = 0.f, c = 0.f;
    for (int i = i0; i < i1; i++) {
        int g = batch[i];
        if (g != curg) {
            atomicAdd(&pooled[(size_t)curg * 64 + lane], acc);
            if (lane == 0) atomicAdd(&cnt[curg], c);
            curg = g; acc = 0.f; c = 0.f;
        }
        acc += fmaxf(b2f(h[pbase + (size_t)i * 16]) * A + B, 0.f);
        c += 1.f;
    }
    atomicAdd(&pooled[(size_t)curg * 64 + lane], acc);
    if (lane == 0) atomicAdd(&cnt[curg], c);
}

// ---- Head --------------------------------------------------------------
__global__ __launch_bounds__(64) void k_head(const float* pooled_c, const float* cnt_c,
                                             const float* pooled_s, const float* cnt_s,
                                             const float* Wf1, const float* bf1_,
                                             const float* Wf2, const float* bf2_,
                                             float* out) {
    __shared__ float W1sm[128 * 64];
    __shared__ float W2sm[128];
    int t = threadIdx.x;
    for (int i = t; i < 128 * 64; i += 64) W1sm[i] = Wf1[i];
    for (int i = t; i < 128; i += 64) W2sm[i] = Wf2[i];
    __syncthreads();
    float bb1 = bf1_[t];
    float b20 = bf2_[0];
    float b21 = bf2_[1];
    for (int g = blockIdx.x; g < G_; g += gridDim.x) {
        float ic = 1.f / fmaxf(cnt_c[g], 1.f);
        float is = 1.f / fmaxf(cnt_s[g], 1.f);
        float hc = pooled_c[(size_t)g * 64 + t] * ic;
        float hs = pooled_s[(size_t)g * 64 + t] * is;
        float s = bb1;
        for (int k = 0; k < 64; k++) s += __shfl(hc, k) * W1sm[k * 64 + t];
        for (int k = 0; k < 64; k++) s += __shfl(hs, k) * W1sm[(64 + k) * 64 + t];
        s = fmaxf(s, 0.f);
        float p0 = s * W2sm[t * 2 + 0];
        float p1 = s * W2sm[t * 2 + 1];
        for (int off = 32; off > 0; off >>= 1) {
            p0 += __shfl_down(p0, off);
            p1 += __shfl_down(p1, off);
        }
        if (t == 0) {
            out[g * 2 + 0] = p0 + b20;
            out[g * 2 + 1] = p1 + b21;
        }
    }
}

extern "C" void kernel_launch(void* const* d_in, const int* in_sizes, int n_in,
                              void* d_out, int out_size, void* d_ws, size_t ws_size,
                              hipStream_t stream) {
    float* out = (float*)d_out;

    if (n_in != 26 || in_sizes[0] != NC_ * 7 || in_sizes[1] != 2 * EC_ ||
        in_sizes[2] != NC_ || in_sizes[3] != NS_ * 7 || in_sizes[4] != 2 * ES_ ||
        in_sizes[5] != NS_ || out_size != G_ * 2) {
        k_fillout<<<(out_size + 255) / 256, 256, 0, stream>>>(out, 7777.0f, out_size);
        return;
    }
    if (ws_size < (size_t)WS_MIN_FALLBACK) {
        k_fillout<<<(out_size + 255) / 256, 256, 0, stream>>>(
            out, 1000.0f + (float)(ws_size >> 20), out_size);
        return;
    }
    const bool big = (ws_size >= (size_t)WS_BIG);

    const float* x_c     = (const float*)d_in[0];
    const int*   ei_c    = (const int*)d_in[1];
    const int*   batch_c = (const int*)d_in[2];
    const float* x_s     = (const float*)d_in[3];
    const int*   ei_s    = (const int*)d_in[4];
    const int*   batch_s = (const int*)d_in[5];
    const float* Wc0  = (const float*)d_in[6];
    const float* bc0  = (const float*)d_in[7];
    const float* gc0  = (const float*)d_in[8];
    const float* bec0 = (const float*)d_in[9];
    const float* Wc1  = (const float*)d_in[10];
    const float* bc1  = (const float*)d_in[11];
    const float* gc1  = (const float*)d_in[12];
    const float* bec1 = (const float*)d_in[13];
    const float* Ws0  = (const float*)d_in[14];
    const float* bs0  = (const float*)d_in[15];
    const float* gs0  = (const float*)d_in[16];
    const float* bes0 = (const float*)d_in[17];
    const float* Ws1  = (const float*)d_in[18];
    const float* bs1  = (const float*)d_in[19];
    const float* gs1  = (const float*)d_in[20];
    const float* bes1 = (const float*)d_in[21];
    const float* Wf1  = (const float*)d_in[22];
    const float* bf1_ = (const float*)d_in[23];
    const float* Wf2  = (const float*)d_in[24];
    const float* bf2_ = (const float*)d_in[25];

    const int NYC = NC_ + 8;
    const int NYS = NS_ + 8;

    // ---- common workspace layout (4-byte words) ----
    int* wsw = (int*)d_ws;
    size_t off = 0;
    float* stats_c  = (float*)(wsw + off); off += 256;
    float* stats_s  = (float*)(wsw + off); off += 256;
    float* pooled_c = (float*)(wsw + off); off += (size_t)G_ * 64;
    float* pooled_s = (float*)(wsw + off); off += (size_t)G_ * 64;
    float* cnt_c    = (float*)(wsw + off); off += G_;
    float* cnt_s    = (float*)(wsw + off); off += G_;
    int*   bcnt_c   = wsw + off; off += NB_C;
    int*   bcnt_s   = wsw + off; off += NB_S;
    size_t zero_words = off;
    int*   bbase_c  = wsw + off; off += NB_C + 1;
    int*   bcur_c   = wsw + off; off += NB_C;
    int*   bbase_s  = wsw + off; off += NB_S + 1;
    int*   bcur_s   = wsw + off; off += NB_S;
    int*   deg_c    = wsw + off; off += NC_;
    int*   start_c  = wsw + off; off += NC_;
    int*   deg_s    = wsw + off; off += NS_;
    int*   start_s  = wsw + off; off += NS_;
    int*   csr_c    = wsw + off; off += CSR_WC;
    int*   csr_s    = wsw + off; off += CSR_WS;
    off = (off + 3) & ~(size_t)3;

    k_zero<<<512, 256, 0, stream>>>(wsw, (int)zero_words);
    k_bhist2<<<384, 256, 0, stream>>>(ei_c + EC_, bcnt_c, ei_s + ES_, bcnt_s);
    k_bscan<<<1, 256, 0, stream>>>(bcnt_c, bbase_c, bcur_c, NB_C,
                                   bcnt_s, bbase_s, bcur_s, NB_S);

    if (big) {
        // ---- big layout: separate solvent buffers, merged pipeline ----
        bf16* h_c = (bf16*)(wsw + off); off += 3201024;   // NC*64 bf16 + tile pad
        bf16* y_c = (bf16*)(wsw + off); off += 3200256;   // 4*NYC*16 bf16
        bf16* h_s = (bf16*)(wsw + off); off += 1601536;   // NS*64 bf16 + tile pad
        bf16* y_s = (bf16*)(wsw + off); off += 1600256;   // 4*NYS*16 bf16
        int*  ebuf_c = (int*)h_c;                 // dead before gather7m writes h_c
        int*  ebuf_s = (int*)h_c + 1600000;
        bf16* u_c = y_c;                          // dead before gemm1m writes y_c
        bf16* u_s = y_s;

        k_bin2<<<587, 256, 0, stream>>>(ei_c, bcur_c, ebuf_c, ei_s, bcur_s, ebuf_s);
        k_build2<<<NB_C + NB_S, 256, 0, stream>>>(bbase_c, ebuf_c, x_c, u_c,
                                                  deg_c, start_c, csr_c,
                                                  bbase_s, ebuf_s, x_s, u_s,
                                                  deg_s, start_s, csr_s);
        k_gather7m<<<NB_C + NB_S, 256, 0, stream>>>(
            u_c, csr_c, start_c, deg_c, Wc0, bc0, h_c, stats_c, NC_,
            u_s, csr_s, start_s, deg_s, Ws0, bs0, h_s, stats_s, NS_, NB_C);
        k_gemm1m<<<768, 256, 0, stream>>>(
            h_c, Wc1, stats_c, gc0, bec0, deg_c, y_c, 1.0f / NC_, NC_, NYC,
            h_s, Ws1, stats_s, gs0, bes0, deg_s, y_s, 1.0f / NS_, NS_, NYS, 512);
        k_gather16<<<3128, 256, 0, stream>>>(y_c, csr_c, start_c, deg_c, bc1,
                                             h_c, stats_c + 128, NC_, NYC);
        k_gather16<<<1564, 256, 0, stream>>>(y_s, csr_s, start_s, deg_s, bs1,
                                             h_s, stats_s + 128, NS_, NYS);
        k_poolm<<<384, 256, 0, stream>>>(
            h_c, stats_c + 128, gc1, bec1, batch_c, pooled_c, cnt_c, 1.0f / NC_, NC_, NYC,
            h_s, stats_s + 128, gs1, bes1, batch_s, pooled_s, cnt_s, 1.0f / NS_, NS_, NYS, 256);
    } else {
        // ---- fallback: round-15 flow, shared buffers ----
        bf16* hbuf = (bf16*)(wsw + off); off += 3201024;
        bf16* ybuf = (bf16*)(wsw + off); off += 3200256;
        int*  ebuf_c = (int*)hbuf;
        int*  ebuf_s = (int*)hbuf + 1600000;
        bf16* ub = ybuf;

        k_bin2<<<587, 256, 0, stream>>>(ei_c, bcur_c, ebuf_c, ei_s, bcur_s, ebuf_s);
        k_build2<<<NB_C + NB_S, 256, 0, stream>>>(bbase_c, ebuf_c, x_c, ub,
                                                  deg_c, start_c, csr_c,
                                                  bbase_s, ebuf_s, (const float*)0, (bf16*)0,
                                                  deg_s, start_s, csr_s);
        // chromo
        k_gather7m<<<NB_C, 256, 0, stream>>>(
            ub, csr_c, start_c, deg_c, Wc0, bc0, hbuf, stats_c, NC_,
            ub, csr_c, start_c, deg_c, Wc0, bc0, hbuf, stats_c, NC_, NB_C);
        k_gemm1m<<<512, 256, 0, stream>>>(
            hbuf, Wc1, stats_c, gc0, bec0, deg_c, ybuf, 1.0f / NC_, NC_, NYC,
            hbuf, Wc1, stats_c, gc0, bec0, deg_c, ybuf, 1.0f / NC_, NC_, NYC, 512);
        k_gather16<<<3128, 256, 0, stream>>>(ybuf, csr_c, start_c, deg_c, bc1,
                                             hbuf, stats_c + 128, NC_, NYC);
        k_poolm<<<256, 256, 0, stream>>>(
            hbuf, stats_c + 128, gc1, bec1, batch_c, pooled_c, cnt_c, 1.0f / NC_, NC_, NYC,
            hbuf, stats_c + 128, gc1, bec1, batch_c, pooled_c, cnt_c, 1.0f / NC_, NC_, NYC, 256);
        // solvent
        k_prep7<<<(NS_ + 256) / 256, 256, 0, stream>>>(x_s, deg_s, ub, NS_);
        k_gather7m<<<NB_S, 256, 0, stream>>>(
            ub, csr_s, start_s, deg_s, Ws0, bs0, hbuf, stats_s, NS_,
            ub, csr_s, start_s, deg_s, Ws0, bs0, hbuf, stats_s, NS_, NB_S);
        k_gemm1m<<<256, 256, 0, stream>>>(
            hbuf, Ws1, stats_s, gs0, bes0, deg_s, ybuf, 1.0f / NS_, NS_, NYS,
            hbuf, Ws1, stats_s, gs0, bes0, deg_s, ybuf, 1.0f / NS_, NS_, NYS, 256);
        k_gather16<<<1564, 256, 0, stream>>>(ybuf, csr_s, start_s, deg_s, bs1,
                                             hbuf, stats_s + 128, NS_, NYS);
        k_poolm<<<256, 256, 0, stream>>>(
            hbuf, stats_s + 128, gs1, bes1, batch_s, pooled_s, cnt_s, 1.0f / NS_, NS_, NYS,
            hbuf, stats_s + 128, gs1, bes1, batch_s, pooled_s, cnt_s, 1.0f / NS_, NS_, NYS, 256);
    }

    k_head<<<128, 64, 0, stream>>>(pooled_c, cnt_c, pooled_s, cnt_s, Wf1, bf1_, Wf2, bf2_, out);
}